// Round 1
// baseline (482.391 us; speedup 1.0000x reference)
//
#include <hip/hip_runtime.h>

namespace {

constexpr int BB   = 32;     // batch
constexpr int NBOX = 50;
constexpr int NCLS = 20;
constexpr int NT   = 10647;  // total anchors
constexpr int NNEG = 1000;
constexpr float EPS = 1e-7f;
constexpr float PI4 = (float)(4.0 / 9.869604401089358);  // 4/pi^2

__device__ __constant__ float c_aw[9] = {10.f/416.f,16.f/416.f,33.f/416.f,30.f/416.f,62.f/416.f,59.f/416.f,116.f/416.f,156.f/416.f,373.f/416.f};
__device__ __constant__ float c_ah[9] = {13.f/416.f,30.f/416.f,23.f/416.f,61.f/416.f,45.f/416.f,119.f/416.f,90.f/416.f,198.f/416.f,326.f/416.f};

__device__ __forceinline__ float dciou(float al, float at, float ar, float ab,
                                       float bl, float bt, float br, float bb,
                                       float atanA, float atanB) {
  float ltx = fmaxf(al, bl), lty = fmaxf(at, bt);
  float rbx = fminf(ar, br), rby = fminf(ab, bb);
  float wx = fmaxf(rbx - ltx, 0.f), wy = fmaxf(rby - lty, 0.f);
  float inter = wx * wy;
  float wa = ar - al, ha = ab - at;
  float wb = br - bl, hb = bb - bt;
  float uni = wa * ha + wb * hb - inter;
  float iou = inter / (uni + EPS);
  float cw = fmaxf(ar, br) - fminf(al, bl);
  float ch = fmaxf(ab, bb) - fminf(at, bt);
  float c2 = cw * cw + ch * ch + EPS;
  float dx = (al + ar) * 0.5f - (bl + br) * 0.5f;
  float dy = (at + ab) * 0.5f - (bt + bb) * 0.5f;
  float rho2 = dx * dx + dy * dy;
  float dat = atanA - atanB;
  float v = PI4 * (dat * dat);
  float alpha = v / (1.f - iou + v + EPS);
  return iou - rho2 / c2 - alpha * v;
}

// K1: decode pred boxes -> pltrb; mx over 50 GT boxes; composite sort key.
__global__ void k_decode_mx(const float* __restrict__ p, const float* __restrict__ boxes,
                            float4* __restrict__ pltrb, unsigned long long* __restrict__ comp) {
  int b = blockIdx.y;
  int j = blockIdx.x * 256 + threadIdx.x;
  __shared__ float sb[NBOX][4];
  __shared__ float satan[NBOX];
  int t = threadIdx.x;
  if (t < NBOX) {
    const float* bp = boxes + (b * NBOX + t) * 4;
    float l = bp[0], tt = bp[1], r = bp[2], d = bp[3];
    sb[t][0] = l; sb[t][1] = tt; sb[t][2] = r; sb[t][3] = d;
    float wa = r - l, ha = d - tt;
    satan[t] = atanf(wa / (ha + EPS));
  }
  __syncthreads();
  if (j >= NT) return;
  int lvl, base, f;
  if (j < 8112)       { lvl = 0; base = 0;     f = 52; }
  else if (j < 10140) { lvl = 1; base = 8112;  f = 26; }
  else                { lvl = 2; base = 10140; f = 13; }
  int jj = j - base;
  int cell = jj / 3, a = jj % 3 + lvl * 3;
  int x = cell % f, y = cell / f;
  float ff = (float)f;
  const float* pr = p + ((size_t)b * NT + j) * 25;
  float px = pr[0] / ff + (float)x / ff;
  float py = pr[1] / ff + (float)y / ff;
  float pw = expf(pr[2]) * c_aw[a];
  float ph = expf(pr[3]) * c_ah[a];
  float pl = px - pw * 0.5f, pt = py - ph * 0.5f;
  float prr = px + pw * 0.5f, pbb = py + ph * 0.5f;
  pltrb[(size_t)b * NT + j] = make_float4(pl, pt, prr, pbb);
  float wb = prr - pl, hb = pbb - pt;
  float atanB = atanf(wb / (hb + EPS));
  float mx = -INFINITY;
  for (int i = 0; i < NBOX; ++i) {
    float v = dciou(sb[i][0], sb[i][1], sb[i][2], sb[i][3], pl, pt, prr, pbb, satan[i], atanB);
    mx = fmaxf(mx, v);
  }
  float key = (mx < 0.5f) ? mx : INFINITY;
  unsigned int u = __float_as_uint(key);
  u = (u & 0x80000000u) ? ~u : (u | 0x80000000u);
  comp[(size_t)b * NT + j] = ((unsigned long long)u << 14) | (unsigned long long)j;
}

// K2: per-image chunked scan -> rank[j] = cumsum(mask)[j] - 1
__global__ void k_scan(const unsigned long long* __restrict__ comp, int* __restrict__ rank) {
  int b = blockIdx.x;
  __shared__ int s[256];
  __shared__ int carry;
  if (threadIdx.x == 0) carry = 0;
  __syncthreads();
  const unsigned long long* c = comp + (size_t)b * NT;
  int* r = rank + (size_t)b * NT;
  for (int start = 0; start < NT; start += 256) {
    int j = start + threadIdx.x;
    int flag = 0;
    if (j < NT) flag = ((c[j] >> 14) < 0xFF800000ull) ? 1 : 0;
    s[threadIdx.x] = flag;
    __syncthreads();
    for (int off = 1; off < 256; off <<= 1) {
      int add = (threadIdx.x >= off) ? s[threadIdx.x - off] : 0;
      __syncthreads();
      s[threadIdx.x] += add;
      __syncthreads();
    }
    int incl = s[threadIdx.x];
    if (j < NT) r[j] = carry + incl - 1;
    __syncthreads();
    if (threadIdx.x == 255) carry += incl;
    __syncthreads();
  }
}

// K3: per-image radix bit-prefix select of the 999th-smallest composite, then
// accumulate l_conf_n over {c <= T} using rank[j] as the p-row index (ref quirk).
__global__ void k_neg(const unsigned long long* __restrict__ comp, const int* __restrict__ rank,
                      const float* __restrict__ p, float* __restrict__ lcn) {
  int b = blockIdx.x;
  const unsigned long long* c = comp + (size_t)b * NT;
  __shared__ int red[256];
  unsigned long long prefix = 0;
  int remaining = NNEG - 1;
  for (int bit = 45; bit >= 0; --bit) {
    unsigned long long himask = ~((1ull << (bit + 1)) - 1ull);
    unsigned long long bitm = 1ull << bit;
    int cnt = 0;
    for (int j = threadIdx.x; j < NT; j += 256) {
      unsigned long long v = c[j];
      if ((v & himask) == prefix && (v & bitm) == 0ull) cnt++;
    }
    red[threadIdx.x] = cnt;
    __syncthreads();
    for (int off = 128; off > 0; off >>= 1) {
      if (threadIdx.x < off) red[threadIdx.x] += red[threadIdx.x + off];
      __syncthreads();
    }
    int total = red[0];
    __syncthreads();
    if (remaining >= total) { prefix |= bitm; remaining -= total; }
  }
  unsigned long long T = prefix;  // exact 999th smallest (composites unique)
  float acc = 0.f;
  const int* r = rank + (size_t)b * NT;
  const float* pb = p + (size_t)b * NT * 25;
  for (int j = threadIdx.x; j < NT; j += 256) {
    if (c[j] <= T) {
      int idx = r[j];
      if (idx < 0) idx += NT;       // JAX negative-index wrap (rank can be -1)
      float pneg = pb[(size_t)idx * 25 + 4];
      float q = 1.f - pneg;
      q = fminf(fmaxf(q, EPS), 1.f - EPS);
      acc += -logf(q);
    }
  }
  __shared__ float redf[256];
  redf[threadIdx.x] = acc;
  __syncthreads();
  for (int off = 128; off > 0; off >>= 1) {
    if (threadIdx.x < off) redf[threadIdx.x] += redf[threadIdx.x + off];
    __syncthreads();
  }
  if (threadIdx.x == 0) lcn[b] = redf[0];
}

// K4: positive losses. One block/image, 8 waves; one wave per box iteration.
__global__ void k_pos(const float* __restrict__ p, const float* __restrict__ boxes,
                      const int* __restrict__ labels, const float4* __restrict__ pltrb,
                      float* __restrict__ lcls, float* __restrict__ lbox, float* __restrict__ lcp) {
  int b = blockIdx.x;
  int tid = threadIdx.x;
  int wave = tid >> 6, lane = tid & 63;
  __shared__ float sb[NBOX][4];
  __shared__ float scx[NBOX], scy[NBOX];
  __shared__ float wcls[8], wbox[8], wcp[8];
  if (tid < NBOX) {
    const float* bp = boxes + (b * NBOX + tid) * 4;
    float l = bp[0], t = bp[1], r = bp[2], d = bp[3];
    sb[tid][0] = l; sb[tid][1] = t; sb[tid][2] = r; sb[tid][3] = d;
    scx[tid] = (l + r) * 0.5f;
    scy[tid] = (t + d) * 0.5f;
  }
  if (tid < 8) { wcls[tid] = 0.f; wbox[tid] = 0.f; wcp[tid] = 0.f; }
  __syncthreads();
  float acc_cls = 0.f, acc_box = 0.f, acc_cp = 0.f;
  for (int i = wave; i < NBOX; i += 8) {
    float fi = (float)i;
    float al = sb[i][0] + fi, at = sb[i][1] + fi, ar = sb[i][2] + fi, ad = sb[i][3] + fi;
    float wa = ar - al, ha = ad - at;
    float atanA = atanf(wa / (ha + EPS));
    float bestv = -INFINITY; int bestm = 1 << 30;
    for (int m = lane; m < 9 * NBOX; m += 64) {
      int jb = m / 9, a = m % 9;
      float fa = (a < 3) ? 52.f : (a < 6 ? 26.f : 13.f);
      float col = floorf(scx[jb] * fa);
      float row = floorf(scy[jb] * fa);
      float ax = col / fa, ay = row / fa;
      float aw = c_aw[a], ah = c_ah[a];
      float fj = (float)jb;
      float bl = (ax - aw * 0.5f) + fj;
      float bt = (ay - ah * 0.5f) + fj;
      float br = (ax + aw * 0.5f) + fj;
      float bd = (ay + ah * 0.5f) + fj;
      float wb = br - bl, hb = bd - bt;
      float atanB = atanf(wb / (hb + EPS));
      float v = dciou(al, at, ar, ad, bl, bt, br, bd, atanA, atanB);
      if (v > bestv) { bestv = v; bestm = m; }
    }
    for (int off = 32; off > 0; off >>= 1) {
      float ov = __shfl_down(bestv, off);
      int om = __shfl_down(bestm, off);
      if (ov > bestv || (ov == bestv && om < bestm)) { bestv = ov; bestm = om; }
    }
    if (lane == 0) {
      int k = bestm % 9;
      int lvl = k / 3;
      float fk = (k < 3) ? 52.f : (k < 6 ? 26.f : 13.f);
      float col = floorf(scx[i] * fk);
      float row = floorf(scy[i] * fk);
      float offc = (lvl == 0) ? 0.f : (lvl == 1 ? 2704.f : 3380.f);
      float offcr = row * fk + col;
      int midx = (int)((offc + offcr) * 3.0f + (float)lvl);  // ref uses +lvl, not +k%3
      const float* pr = p + ((size_t)b * NT + midx) * 25;
      int lab = labels[b * NBOX + i] - 1;
      float lc = 0.f;
      for (int cidx = 0; cidx < NCLS; ++cidx) {
        float pc = pr[5 + cidx];
        pc = fminf(fmaxf(pc, EPS), 1.f - EPS);
        float tt = (cidx == lab) ? 1.f : 0.f;
        lc += -(tt * logf(pc) + (1.f - tt) * logf(1.f - pc));
      }
      acc_cls += lc;
      float pc4 = pr[4];
      pc4 = fminf(fmaxf(pc4, EPS), 1.f - EPS);
      acc_cp += -logf(pc4);
      float4 pb4 = pltrb[(size_t)b * NT + midx];
      float wb = pb4.z - pb4.x, hb = pb4.w - pb4.y;
      float atanB = atanf(wb / (hb + EPS));
      float bl0 = sb[i][0], bt0 = sb[i][1], br0 = sb[i][2], bd0 = sb[i][3];
      float wa0 = br0 - bl0, ha0 = bd0 - bt0;
      float atanA0 = atanf(wa0 / (ha0 + EPS));
      float cp = dciou(bl0, bt0, br0, bd0, pb4.x, pb4.y, pb4.z, pb4.w, atanA0, atanB);
      float w = 2.f - wa0 * ha0;
      acc_box += w * (1.f - cp);
    }
  }
  if (lane == 0) { wcls[wave] = acc_cls; wbox[wave] = acc_box; wcp[wave] = acc_cp; }
  __syncthreads();
  if (tid == 0) {
    float a = 0.f, bx = 0.f, cp = 0.f;
    for (int w2 = 0; w2 < 8; ++w2) { a += wcls[w2]; bx += wbox[w2]; cp += wcp[w2]; }
    lcls[b] = a / (float)NBOX;
    lbox[b] = bx / (float)NBOX;
    lcp[b] = cp / (float)NBOX;
  }
}

__global__ void k_final(const float* __restrict__ lcls, const float* __restrict__ lbox,
                        const float* __restrict__ lcp, const float* __restrict__ lcn,
                        float* __restrict__ out) {
  if (threadIdx.x == 0) {
    float s = 0.f;
    for (int b = 0; b < BB; ++b) s += lcls[b] + lbox[b] + lcp[b] + lcn[b];
    out[0] = s / (float)BB;
  }
}

}  // namespace

extern "C" void kernel_launch(void* const* d_in, const int* in_sizes, int n_in,
                              void* d_out, int out_size, void* d_ws, size_t ws_size,
                              hipStream_t stream) {
  const float* p      = (const float*)d_in[0];
  const float* boxes  = (const float*)d_in[1];
  const int*   labels = (const int*)d_in[2];
  float* out = (float*)d_out;

  char* ws = (char*)d_ws;
  size_t off = 0;
  float4* pltrb = (float4*)(ws + off);             off += (size_t)BB * NT * sizeof(float4);
  unsigned long long* comp = (unsigned long long*)(ws + off); off += (size_t)BB * NT * sizeof(unsigned long long);
  int* rank = (int*)(ws + off);                    off += (size_t)BB * NT * sizeof(int);
  float* lcls = (float*)(ws + off);                off += BB * sizeof(float);
  float* lbox = (float*)(ws + off);                off += BB * sizeof(float);
  float* lcp  = (float*)(ws + off);                off += BB * sizeof(float);
  float* lcn  = (float*)(ws + off);                off += BB * sizeof(float);

  dim3 g1((NT + 255) / 256, BB);
  k_decode_mx<<<g1, 256, 0, stream>>>(p, boxes, pltrb, comp);
  k_scan<<<BB, 256, 0, stream>>>(comp, rank);
  k_neg<<<BB, 256, 0, stream>>>(comp, rank, p, lcn);
  k_pos<<<BB, 512, 0, stream>>>(p, boxes, labels, pltrb, lcls, lbox, lcp);
  k_final<<<1, 64, 0, stream>>>(lcls, lbox, lcp, lcn, out);
}

// Round 2
// 131.256 us; speedup vs baseline: 3.6752x; 3.6752x over previous
//
#include <hip/hip_runtime.h>

namespace {

constexpr int BB   = 32;     // batch
constexpr int NBOX = 50;
constexpr int NCLS = 20;
constexpr int NT   = 10647;  // total anchors
constexpr int NNEG = 1000;
constexpr float EPS = 1e-7f;
constexpr float PI4 = (float)(4.0 / 9.869604401089358);  // 4/pi^2

__device__ __constant__ float c_aw[9] = {10.f/416.f,16.f/416.f,33.f/416.f,30.f/416.f,62.f/416.f,59.f/416.f,116.f/416.f,156.f/416.f,373.f/416.f};
__device__ __constant__ float c_ah[9] = {13.f/416.f,30.f/416.f,23.f/416.f,61.f/416.f,45.f/416.f,119.f/416.f,90.f/416.f,198.f/416.f,326.f/416.f};

__device__ __forceinline__ float dciou(float al, float at, float ar, float ab,
                                       float bl, float bt, float br, float bb,
                                       float atanA, float atanB) {
  float ltx = fmaxf(al, bl), lty = fmaxf(at, bt);
  float rbx = fminf(ar, br), rby = fminf(ab, bb);
  float wx = fmaxf(rbx - ltx, 0.f), wy = fmaxf(rby - lty, 0.f);
  float inter = wx * wy;
  float wa = ar - al, ha = ab - at;
  float wb = br - bl, hb = bb - bt;
  float uni = wa * ha + wb * hb - inter;
  float iou = inter / (uni + EPS);
  float cw = fmaxf(ar, br) - fminf(al, bl);
  float ch = fmaxf(ab, bb) - fminf(at, bt);
  float c2 = cw * cw + ch * ch + EPS;
  float dx = (al + ar) * 0.5f - (bl + br) * 0.5f;
  float dy = (at + ab) * 0.5f - (bt + bb) * 0.5f;
  float rho2 = dx * dx + dy * dy;
  float dat = atanA - atanB;
  float v = PI4 * (dat * dat);
  float alpha = v / (1.f - iou + v + EPS);
  return iou - rho2 / c2 - alpha * v;
}

__device__ __forceinline__ int wave_incl_scan(int x, int lane) {
  #pragma unroll
  for (int off = 1; off < 64; off <<= 1) {
    int y = __shfl_up(x, off);
    if (lane >= off) x += y;
  }
  return x;
}

// K1: decode pred boxes -> pltrb; mx over 50 GT boxes; composite sort key.
__global__ void k_decode_mx(const float* __restrict__ p, const float* __restrict__ boxes,
                            float4* __restrict__ pltrb, unsigned long long* __restrict__ comp) {
  int b = blockIdx.y;
  int j = blockIdx.x * 256 + threadIdx.x;
  __shared__ float sb[NBOX][4];
  __shared__ float satan[NBOX];
  int t = threadIdx.x;
  if (t < NBOX) {
    const float* bp = boxes + (b * NBOX + t) * 4;
    float l = bp[0], tt = bp[1], r = bp[2], d = bp[3];
    sb[t][0] = l; sb[t][1] = tt; sb[t][2] = r; sb[t][3] = d;
    float wa = r - l, ha = d - tt;
    satan[t] = atanf(wa / (ha + EPS));
  }
  __syncthreads();
  if (j >= NT) return;
  int lvl, base, f;
  if (j < 8112)       { lvl = 0; base = 0;     f = 52; }
  else if (j < 10140) { lvl = 1; base = 8112;  f = 26; }
  else                { lvl = 2; base = 10140; f = 13; }
  int jj = j - base;
  int cell = jj / 3, a = jj % 3 + lvl * 3;
  int x = cell % f, y = cell / f;
  float ff = (float)f;
  const float* pr = p + ((size_t)b * NT + j) * 25;
  float px = pr[0] / ff + (float)x / ff;
  float py = pr[1] / ff + (float)y / ff;
  float pw = expf(pr[2]) * c_aw[a];
  float ph = expf(pr[3]) * c_ah[a];
  float pl = px - pw * 0.5f, pt = py - ph * 0.5f;
  float prr = px + pw * 0.5f, pbb = py + ph * 0.5f;
  pltrb[(size_t)b * NT + j] = make_float4(pl, pt, prr, pbb);
  float wb = prr - pl, hb = pbb - pt;
  float atanB = atanf(wb / (hb + EPS));
  float mx = -INFINITY;
  for (int i = 0; i < NBOX; ++i) {
    float v = dciou(sb[i][0], sb[i][1], sb[i][2], sb[i][3], pl, pt, prr, pbb, satan[i], atanB);
    mx = fmaxf(mx, v);
  }
  float key = (mx < 0.5f) ? mx : INFINITY;
  unsigned int u = __float_as_uint(key);
  u = (u & 0x80000000u) ? ~u : (u | 0x80000000u);
  comp[(size_t)b * NT + j] = ((unsigned long long)u << 14) | (unsigned long long)j;
}

// K2 (fused select + scan + BCE): per-image 4-pass radix-histogram select of the
// 999th-smallest composite; then a fused cumsum(mask)-1 block scan over j to get
// the rank index used as the p-row (ref quirk), accumulating l_conf_n.
__global__ __launch_bounds__(1024) void k_neg2(const unsigned long long* __restrict__ comp,
                                               const float* __restrict__ p,
                                               float* __restrict__ lcn) {
  int b = blockIdx.x;
  const unsigned long long* c = comp + (size_t)b * NT;
  const int tid = threadIdx.x, lane = tid & 63, wave = tid >> 6;

  __shared__ int hist[4096];
  __shared__ int s_w[16];
  __shared__ unsigned long long s_pref;
  __shared__ int s_rem;
  __shared__ int s_carry;
  __shared__ int s_digit;
  __shared__ int s_rem_next;
  __shared__ float s_facc[16];

  // Hoist the image's composites into registers: 11 per thread (chunk-major).
  unsigned long long v[11];
  #pragma unroll
  for (int k = 0; k < 11; ++k) {
    int j = k * 1024 + tid;
    v[k] = (j < NT) ? c[j] : ~0ull;   // pad > any 46-bit composite; excluded by prefix check
  }

  if (tid == 0) { s_pref = 0ull; s_rem = NNEG - 1; s_carry = 0; }
  __syncthreads();

  // 4 radix passes over digit windows [47:36],[35:24],[23:12],[11:0].
  for (int pass = 0; pass < 4; ++pass) {
    int lo = 36 - pass * 12;
    for (int h = tid; h < 4096; h += 1024) hist[h] = 0;
    __syncthreads();
    unsigned long long pref = s_pref;
    #pragma unroll
    for (int k = 0; k < 11; ++k) {
      unsigned long long x = v[k];
      if ((x >> (lo + 12)) == (pref >> (lo + 12)))
        atomicAdd(&hist[(int)((x >> lo) & 4095ull)], 1);
    }
    __syncthreads();
    // Block-wide exclusive scan over 4096 buckets (4 per thread), locate target.
    int base = tid * 4;
    int c0 = hist[base], c1 = hist[base + 1], c2 = hist[base + 2], c3 = hist[base + 3];
    int tsum = c0 + c1 + c2 + c3;
    int incl = wave_incl_scan(tsum, lane);
    if (lane == 63) s_w[wave] = incl;
    __syncthreads();
    if (wave == 0) {
      int wv = (lane < 16) ? s_w[lane] : 0;
      int wincl = wave_incl_scan(wv, lane);
      if (lane < 16) s_w[lane] = wincl - wv;  // exclusive wave offsets
    }
    __syncthreads();
    int excl = incl - tsum + s_w[wave];
    int rem = s_rem;
    int p0 = excl, p1 = p0 + c0, p2 = p1 + c1, p3 = p2 + c2;
    if (rem >= p0 && rem < p0 + c0) { s_digit = base + 0; s_rem_next = rem - p0; }
    if (rem >= p1 && rem < p1 + c1) { s_digit = base + 1; s_rem_next = rem - p1; }
    if (rem >= p2 && rem < p2 + c2) { s_digit = base + 2; s_rem_next = rem - p2; }
    if (rem >= p3 && rem < p3 + c3) { s_digit = base + 3; s_rem_next = rem - p3; }
    __syncthreads();
    if (tid == 0) {
      s_pref |= ((unsigned long long)s_digit) << lo;
      s_rem = s_rem_next;
    }
    __syncthreads();
  }
  const unsigned long long T = s_pref;  // exact 999th-smallest composite (unique keys)

  // Fused scan (rank = cumsum(mask)-1) + selection (c<=T) + BCE accumulate.
  float acc = 0.f;
  const float* pb = p + (size_t)b * NT * 25;
  #pragma unroll
  for (int k = 0; k < 11; ++k) {
    unsigned long long x = v[k];
    int flag = ((x >> 14) < 0xFF800000ull) ? 1 : 0;  // finite ordkey => masked
    int incl = wave_incl_scan(flag, lane);
    if (lane == 63) s_w[wave] = incl;
    __syncthreads();
    if (wave == 0) {
      int wv = (lane < 16) ? s_w[lane] : 0;
      int wincl = wave_incl_scan(wv, lane);
      if (lane < 16) s_w[lane] = wincl - wv;
    }
    __syncthreads();
    int rank = s_carry + s_w[wave] + incl - 1;
    if (x <= T) {
      int idx = rank;
      if (idx < 0) idx += NT;  // JAX negative-index wrap (rank can be -1)
      float q = 1.f - pb[(size_t)idx * 25 + 4];
      q = fminf(fmaxf(q, EPS), 1.f - EPS);
      acc += -logf(q);
    }
    __syncthreads();
    if (tid == 1023) s_carry += s_w[15] + incl;  // chunk total
    __syncthreads();
  }

  // Reduce acc across the block.
  #pragma unroll
  for (int off = 32; off > 0; off >>= 1) acc += __shfl_down(acc, off);
  if (lane == 0) s_facc[wave] = acc;
  __syncthreads();
  if (tid == 0) {
    float s = 0.f;
    #pragma unroll
    for (int w = 0; w < 16; ++w) s += s_facc[w];
    lcn[b] = s;
  }
}

// K4: positive losses. One block/image, 8 waves; one wave per box iteration.
__global__ void k_pos(const float* __restrict__ p, const float* __restrict__ boxes,
                      const int* __restrict__ labels, const float4* __restrict__ pltrb,
                      float* __restrict__ lcls, float* __restrict__ lbox, float* __restrict__ lcp) {
  int b = blockIdx.x;
  int tid = threadIdx.x;
  int wave = tid >> 6, lane = tid & 63;
  __shared__ float sb[NBOX][4];
  __shared__ float scx[NBOX], scy[NBOX];
  __shared__ float wcls[8], wbox[8], wcp[8];
  if (tid < NBOX) {
    const float* bp = boxes + (b * NBOX + tid) * 4;
    float l = bp[0], t = bp[1], r = bp[2], d = bp[3];
    sb[tid][0] = l; sb[tid][1] = t; sb[tid][2] = r; sb[tid][3] = d;
    scx[tid] = (l + r) * 0.5f;
    scy[tid] = (t + d) * 0.5f;
  }
  if (tid < 8) { wcls[tid] = 0.f; wbox[tid] = 0.f; wcp[tid] = 0.f; }
  __syncthreads();
  float acc_cls = 0.f, acc_box = 0.f, acc_cp = 0.f;
  for (int i = wave; i < NBOX; i += 8) {
    float fi = (float)i;
    float al = sb[i][0] + fi, at = sb[i][1] + fi, ar = sb[i][2] + fi, ad = sb[i][3] + fi;
    float wa = ar - al, ha = ad - at;
    float atanA = atanf(wa / (ha + EPS));
    float bestv = -INFINITY; int bestm = 1 << 30;
    for (int m = lane; m < 9 * NBOX; m += 64) {
      int jb = m / 9, a = m % 9;
      float fa = (a < 3) ? 52.f : (a < 6 ? 26.f : 13.f);
      float col = floorf(scx[jb] * fa);
      float row = floorf(scy[jb] * fa);
      float ax = col / fa, ay = row / fa;
      float aw = c_aw[a], ah = c_ah[a];
      float fj = (float)jb;
      float bl = (ax - aw * 0.5f) + fj;
      float bt = (ay - ah * 0.5f) + fj;
      float br = (ax + aw * 0.5f) + fj;
      float bd = (ay + ah * 0.5f) + fj;
      float wb = br - bl, hb = bd - bt;
      float atanB = atanf(wb / (hb + EPS));
      float v = dciou(al, at, ar, ad, bl, bt, br, bd, atanA, atanB);
      if (v > bestv) { bestv = v; bestm = m; }
    }
    for (int off = 32; off > 0; off >>= 1) {
      float ov = __shfl_down(bestv, off);
      int om = __shfl_down(bestm, off);
      if (ov > bestv || (ov == bestv && om < bestm)) { bestv = ov; bestm = om; }
    }
    if (lane == 0) {
      int k = bestm % 9;
      int lvl = k / 3;
      float fk = (k < 3) ? 52.f : (k < 6 ? 26.f : 13.f);
      float col = floorf(scx[i] * fk);
      float row = floorf(scy[i] * fk);
      float offc = (lvl == 0) ? 0.f : (lvl == 1 ? 2704.f : 3380.f);
      float offcr = row * fk + col;
      int midx = (int)((offc + offcr) * 3.0f + (float)lvl);  // ref uses +lvl, not +k%3
      const float* pr = p + ((size_t)b * NT + midx) * 25;
      int lab = labels[b * NBOX + i] - 1;
      float lc = 0.f;
      for (int cidx = 0; cidx < NCLS; ++cidx) {
        float pc = pr[5 + cidx];
        pc = fminf(fmaxf(pc, EPS), 1.f - EPS);
        float tt = (cidx == lab) ? 1.f : 0.f;
        lc += -(tt * logf(pc) + (1.f - tt) * logf(1.f - pc));
      }
      acc_cls += lc;
      float pc4 = pr[4];
      pc4 = fminf(fmaxf(pc4, EPS), 1.f - EPS);
      acc_cp += -logf(pc4);
      float4 pb4 = pltrb[(size_t)b * NT + midx];
      float wb = pb4.z - pb4.x, hb = pb4.w - pb4.y;
      float atanB = atanf(wb / (hb + EPS));
      float bl0 = sb[i][0], bt0 = sb[i][1], br0 = sb[i][2], bd0 = sb[i][3];
      float wa0 = br0 - bl0, ha0 = bd0 - bt0;
      float atanA0 = atanf(wa0 / (ha0 + EPS));
      float cp = dciou(bl0, bt0, br0, bd0, pb4.x, pb4.y, pb4.z, pb4.w, atanA0, atanB);
      float w = 2.f - wa0 * ha0;
      acc_box += w * (1.f - cp);
    }
  }
  if (lane == 0) { wcls[wave] = acc_cls; wbox[wave] = acc_box; wcp[wave] = acc_cp; }
  __syncthreads();
  if (tid == 0) {
    float a = 0.f, bx = 0.f, cp = 0.f;
    for (int w2 = 0; w2 < 8; ++w2) { a += wcls[w2]; bx += wbox[w2]; cp += wcp[w2]; }
    lcls[b] = a / (float)NBOX;
    lbox[b] = bx / (float)NBOX;
    lcp[b] = cp / (float)NBOX;
  }
}

__global__ void k_final(const float* __restrict__ lcls, const float* __restrict__ lbox,
                        const float* __restrict__ lcp, const float* __restrict__ lcn,
                        float* __restrict__ out) {
  if (threadIdx.x == 0) {
    float s = 0.f;
    for (int b = 0; b < BB; ++b) s += lcls[b] + lbox[b] + lcp[b] + lcn[b];
    out[0] = s / (float)BB;
  }
}

}  // namespace

extern "C" void kernel_launch(void* const* d_in, const int* in_sizes, int n_in,
                              void* d_out, int out_size, void* d_ws, size_t ws_size,
                              hipStream_t stream) {
  const float* p      = (const float*)d_in[0];
  const float* boxes  = (const float*)d_in[1];
  const int*   labels = (const int*)d_in[2];
  float* out = (float*)d_out;

  char* ws = (char*)d_ws;
  size_t off = 0;
  float4* pltrb = (float4*)(ws + off);             off += (size_t)BB * NT * sizeof(float4);
  unsigned long long* comp = (unsigned long long*)(ws + off); off += (size_t)BB * NT * sizeof(unsigned long long);
  float* lcls = (float*)(ws + off);                off += BB * sizeof(float);
  float* lbox = (float*)(ws + off);                off += BB * sizeof(float);
  float* lcp  = (float*)(ws + off);                off += BB * sizeof(float);
  float* lcn  = (float*)(ws + off);                off += BB * sizeof(float);

  dim3 g1((NT + 255) / 256, BB);
  k_decode_mx<<<g1, 256, 0, stream>>>(p, boxes, pltrb, comp);
  k_neg2<<<BB, 1024, 0, stream>>>(comp, p, lcn);
  k_pos<<<BB, 512, 0, stream>>>(p, boxes, labels, pltrb, lcls, lbox, lcp);
  k_final<<<1, 64, 0, stream>>>(lcls, lbox, lcp, lcn, out);
}

// Round 3
// 84.465 us; speedup vs baseline: 5.7112x; 1.5540x over previous
//
#include <hip/hip_runtime.h>

namespace {

constexpr int BB   = 32;     // batch
constexpr int NBOX = 50;
constexpr int NCLS = 20;
constexpr int NT   = 10647;  // total anchors
constexpr int NNEG = 1000;
constexpr float EPS = 1e-7f;
constexpr float PI4 = (float)(4.0 / 9.869604401089358);  // 4/pi^2

__device__ __constant__ float c_aw[9] = {10.f/416.f,16.f/416.f,33.f/416.f,30.f/416.f,62.f/416.f,59.f/416.f,116.f/416.f,156.f/416.f,373.f/416.f};
__device__ __constant__ float c_ah[9] = {13.f/416.f,30.f/416.f,23.f/416.f,61.f/416.f,45.f/416.f,119.f/416.f,90.f/416.f,198.f/416.f,326.f/416.f};

__device__ __forceinline__ float dciou(float al, float at, float ar, float ab,
                                       float bl, float bt, float br, float bb,
                                       float atanA, float atanB) {
  float ltx = fmaxf(al, bl), lty = fmaxf(at, bt);
  float rbx = fminf(ar, br), rby = fminf(ab, bb);
  float wx = fmaxf(rbx - ltx, 0.f), wy = fmaxf(rby - lty, 0.f);
  float inter = wx * wy;
  float wa = ar - al, ha = ab - at;
  float wb = br - bl, hb = bb - bt;
  float uni = wa * ha + wb * hb - inter;
  float iou = inter / (uni + EPS);
  float cw = fmaxf(ar, br) - fminf(al, bl);
  float ch = fmaxf(ab, bb) - fminf(at, bt);
  float c2 = cw * cw + ch * ch + EPS;
  float dx = (al + ar) * 0.5f - (bl + br) * 0.5f;
  float dy = (at + ab) * 0.5f - (bt + bb) * 0.5f;
  float rho2 = dx * dx + dy * dy;
  float dat = atanA - atanB;
  float v = PI4 * (dat * dat);
  float alpha = v / (1.f - iou + v + EPS);
  return iou - rho2 / c2 - alpha * v;
}

__device__ __forceinline__ int wave_incl_scan(int x, int lane) {
  #pragma unroll
  for (int off = 1; off < 64; off <<= 1) {
    int y = __shfl_up(x, off);
    if (lane >= off) x += y;
  }
  return x;
}

// K1: decode pred boxes -> pltrb; mx over 50 GT boxes; composite sort key.
__global__ void k_decode_mx(const float* __restrict__ p, const float* __restrict__ boxes,
                            float4* __restrict__ pltrb, unsigned long long* __restrict__ comp) {
  int b = blockIdx.y;
  int j = blockIdx.x * 256 + threadIdx.x;
  __shared__ float sb[NBOX][4];
  __shared__ float satan[NBOX];
  int t = threadIdx.x;
  if (t < NBOX) {
    const float* bp = boxes + (b * NBOX + t) * 4;
    float l = bp[0], tt = bp[1], r = bp[2], d = bp[3];
    sb[t][0] = l; sb[t][1] = tt; sb[t][2] = r; sb[t][3] = d;
    float wa = r - l, ha = d - tt;
    satan[t] = atanf(wa / (ha + EPS));
  }
  __syncthreads();
  if (j >= NT) return;
  int lvl, base, f;
  if (j < 8112)       { lvl = 0; base = 0;     f = 52; }
  else if (j < 10140) { lvl = 1; base = 8112;  f = 26; }
  else                { lvl = 2; base = 10140; f = 13; }
  int jj = j - base;
  int cell = jj / 3, a = jj % 3 + lvl * 3;
  int x = cell % f, y = cell / f;
  float ff = (float)f;
  const float* pr = p + ((size_t)b * NT + j) * 25;
  float px = pr[0] / ff + (float)x / ff;
  float py = pr[1] / ff + (float)y / ff;
  float pw = expf(pr[2]) * c_aw[a];
  float ph = expf(pr[3]) * c_ah[a];
  float pl = px - pw * 0.5f, pt = py - ph * 0.5f;
  float prr = px + pw * 0.5f, pbb = py + ph * 0.5f;
  pltrb[(size_t)b * NT + j] = make_float4(pl, pt, prr, pbb);
  float wb = prr - pl, hb = pbb - pt;
  float atanB = atanf(wb / (hb + EPS));
  float mx = -INFINITY;
  for (int i = 0; i < NBOX; ++i) {
    float v = dciou(sb[i][0], sb[i][1], sb[i][2], sb[i][3], pl, pt, prr, pbb, satan[i], atanB);
    mx = fmaxf(mx, v);
  }
  float key = (mx < 0.5f) ? mx : INFINITY;
  unsigned int u = __float_as_uint(key);
  u = (u & 0x80000000u) ? ~u : (u | 0x80000000u);
  comp[(size_t)b * NT + j] = ((unsigned long long)u << 14) | (unsigned long long)j;
}

// K2 (fused select + scan + BCE): per-image 4-pass radix-histogram select of the
// 999th-smallest composite; then a fused cumsum(mask)-1 block scan over j to get
// the rank index used as the p-row (ref quirk), accumulating l_conf_n.
__global__ __launch_bounds__(1024) void k_neg2(const unsigned long long* __restrict__ comp,
                                               const float* __restrict__ p,
                                               float* __restrict__ lcn) {
  int b = blockIdx.x;
  const unsigned long long* c = comp + (size_t)b * NT;
  const int tid = threadIdx.x, lane = tid & 63, wave = tid >> 6;

  __shared__ int hist[4096];
  __shared__ int s_w[16];
  __shared__ unsigned long long s_pref;
  __shared__ int s_rem;
  __shared__ int s_carry;
  __shared__ int s_digit;
  __shared__ int s_rem_next;
  __shared__ float s_facc[16];

  // Hoist the image's composites into registers: 11 per thread (chunk-major).
  unsigned long long v[11];
  #pragma unroll
  for (int k = 0; k < 11; ++k) {
    int j = k * 1024 + tid;
    v[k] = (j < NT) ? c[j] : ~0ull;   // pad > any 46-bit composite; excluded by prefix check
  }

  if (tid == 0) { s_pref = 0ull; s_rem = NNEG - 1; s_carry = 0; }
  __syncthreads();

  // 4 radix passes over digit windows [47:36],[35:24],[23:12],[11:0].
  for (int pass = 0; pass < 4; ++pass) {
    int lo = 36 - pass * 12;
    for (int h = tid; h < 4096; h += 1024) hist[h] = 0;
    __syncthreads();
    unsigned long long pref = s_pref;
    #pragma unroll
    for (int k = 0; k < 11; ++k) {
      unsigned long long x = v[k];
      if ((x >> (lo + 12)) == (pref >> (lo + 12)))
        atomicAdd(&hist[(int)((x >> lo) & 4095ull)], 1);
    }
    __syncthreads();
    // Block-wide exclusive scan over 4096 buckets (4 per thread), locate target.
    int base = tid * 4;
    int c0 = hist[base], c1 = hist[base + 1], c2 = hist[base + 2], c3 = hist[base + 3];
    int tsum = c0 + c1 + c2 + c3;
    int incl = wave_incl_scan(tsum, lane);
    if (lane == 63) s_w[wave] = incl;
    __syncthreads();
    if (wave == 0) {
      int wv = (lane < 16) ? s_w[lane] : 0;
      int wincl = wave_incl_scan(wv, lane);
      if (lane < 16) s_w[lane] = wincl - wv;  // exclusive wave offsets
    }
    __syncthreads();
    int excl = incl - tsum + s_w[wave];
    int rem = s_rem;
    int p0 = excl, p1 = p0 + c0, p2 = p1 + c1, p3 = p2 + c2;
    if (rem >= p0 && rem < p0 + c0) { s_digit = base + 0; s_rem_next = rem - p0; }
    if (rem >= p1 && rem < p1 + c1) { s_digit = base + 1; s_rem_next = rem - p1; }
    if (rem >= p2 && rem < p2 + c2) { s_digit = base + 2; s_rem_next = rem - p2; }
    if (rem >= p3 && rem < p3 + c3) { s_digit = base + 3; s_rem_next = rem - p3; }
    __syncthreads();
    if (tid == 0) {
      s_pref |= ((unsigned long long)s_digit) << lo;
      s_rem = s_rem_next;
    }
    __syncthreads();
  }
  const unsigned long long T = s_pref;  // exact 999th-smallest composite (unique keys)

  // Fused scan (rank = cumsum(mask)-1) + selection (c<=T) + BCE accumulate.
  float acc = 0.f;
  const float* pb = p + (size_t)b * NT * 25;
  #pragma unroll
  for (int k = 0; k < 11; ++k) {
    unsigned long long x = v[k];
    int flag = ((x >> 14) < 0xFF800000ull) ? 1 : 0;  // finite ordkey => masked
    int incl = wave_incl_scan(flag, lane);
    if (lane == 63) s_w[wave] = incl;
    __syncthreads();
    if (wave == 0) {
      int wv = (lane < 16) ? s_w[lane] : 0;
      int wincl = wave_incl_scan(wv, lane);
      if (lane < 16) s_w[lane] = wincl - wv;
    }
    __syncthreads();
    int rank = s_carry + s_w[wave] + incl - 1;
    if (x <= T) {
      int idx = rank;
      if (idx < 0) idx += NT;  // JAX negative-index wrap (rank can be -1)
      float q = 1.f - pb[(size_t)idx * 25 + 4];
      q = fminf(fmaxf(q, EPS), 1.f - EPS);
      acc += -logf(q);
    }
    __syncthreads();
    if (tid == 1023) s_carry += s_w[15] + incl;  // chunk total
    __syncthreads();
  }

  // Reduce acc across the block.
  #pragma unroll
  for (int off = 32; off > 0; off >>= 1) acc += __shfl_down(acc, off);
  if (lane == 0) s_facc[wave] = acc;
  __syncthreads();
  if (tid == 0) {
    float s = 0.f;
    #pragma unroll
    for (int w = 0; w < 16; ++w) s += s_facc[w];
    lcn[b] = s;
  }
}

// K3: positive losses. One wave per (image, box): grid (NBOX, BB) x 64 threads.
// Argmax over 450 candidates (8/lane), then parallel 20-class BCE (1 class/lane).
__global__ __launch_bounds__(64) void k_pos(const float* __restrict__ p, const float* __restrict__ boxes,
                      const int* __restrict__ labels, const float4* __restrict__ pltrb,
                      float* __restrict__ pcls, float* __restrict__ pbox, float* __restrict__ pcp) {
  const int i = blockIdx.x;       // box
  const int b = blockIdx.y;       // image
  const int lane = threadIdx.x;   // 0..63

  __shared__ float scx[NBOX], scy[NBOX];
  if (lane < NBOX) {
    const float* bp = boxes + (b * NBOX + lane) * 4;
    float l = bp[0], t = bp[1], r = bp[2], d = bp[3];
    scx[lane] = (l + r) * 0.5f;
    scy[lane] = (t + d) * 0.5f;
  }
  __syncthreads();

  // Own box (broadcast load through cache).
  const float* bi = boxes + (b * NBOX + i) * 4;
  float bl0 = bi[0], bt0 = bi[1], br0 = bi[2], bd0 = bi[3];
  float fi = (float)i;
  float al = bl0 + fi, at = bt0 + fi, ar = br0 + fi, ad = bd0 + fi;
  float wa = ar - al, ha = ad - at;
  float atanA = atanf(wa / (ha + EPS));

  float bestv = -INFINITY; int bestm = 1 << 30;
  #pragma unroll
  for (int m = lane; m < 9 * NBOX; m += 64) {
    int jb = m / 9, a = m % 9;
    float fa = (a < 3) ? 52.f : (a < 6 ? 26.f : 13.f);
    float col = floorf(scx[jb] * fa);
    float row = floorf(scy[jb] * fa);
    float ax = col / fa, ay = row / fa;
    float aw = c_aw[a], ah = c_ah[a];
    float fj = (float)jb;
    float bl = (ax - aw * 0.5f) + fj;
    float bt = (ay - ah * 0.5f) + fj;
    float br = (ax + aw * 0.5f) + fj;
    float bd = (ay + ah * 0.5f) + fj;
    float wb = br - bl, hb = bd - bt;
    float atanB = atanf(wb / (hb + EPS));
    float v = dciou(al, at, ar, ad, bl, bt, br, bd, atanA, atanB);
    if (v > bestv) { bestv = v; bestm = m; }
  }
  // Butterfly argmax (first-index tie-break = smallest m).
  #pragma unroll
  for (int off = 32; off > 0; off >>= 1) {
    float ov = __shfl_down(bestv, off);
    int om = __shfl_down(bestm, off);
    if (ov > bestv || (ov == bestv && om < bestm)) { bestv = ov; bestm = om; }
  }
  int bm = __shfl(bestm, 0);

  int k = bm % 9;
  int lvl = k / 3;
  float fk = (k < 3) ? 52.f : (k < 6 ? 26.f : 13.f);
  float col = floorf(scx[i] * fk);
  float row = floorf(scy[i] * fk);
  float offc = (lvl == 0) ? 0.f : (lvl == 1 ? 2704.f : 3380.f);
  int midx = (int)((offc + row * fk + col) * 3.0f + (float)lvl);  // ref uses +lvl, not +k%3

  const float* pr = p + ((size_t)b * NT + midx) * 25;
  int lab = labels[b * NBOX + i] - 1;

  // Parallel class BCE: one class per lane (lanes 0..19).
  float lc = 0.f;
  if (lane < NCLS) {
    float pc = pr[5 + lane];
    pc = fminf(fmaxf(pc, EPS), 1.f - EPS);
    float tt = (lane == lab) ? 1.f : 0.f;
    lc = -(tt * logf(pc) + (1.f - tt) * logf(1.f - pc));
  }
  #pragma unroll
  for (int off = 32; off > 0; off >>= 1) lc += __shfl_down(lc, off);

  if (lane == 0) {
    pcls[b * NBOX + i] = lc;
    float pc4 = pr[4];
    pc4 = fminf(fmaxf(pc4, EPS), 1.f - EPS);
    pcp[b * NBOX + i] = -logf(pc4);
    float4 pb4 = pltrb[(size_t)b * NT + midx];
    float wb = pb4.z - pb4.x, hb = pb4.w - pb4.y;
    float atanB = atanf(wb / (hb + EPS));
    float wa0 = br0 - bl0, ha0 = bd0 - bt0;
    float atanA0 = atanf(wa0 / (ha0 + EPS));
    float cp = dciou(bl0, bt0, br0, bd0, pb4.x, pb4.y, pb4.z, pb4.w, atanA0, atanB);
    float w = 2.f - wa0 * ha0;
    pbox[b * NBOX + i] = w * (1.f - cp);
  }
}

// K4: final reduce. Lane b (<32) sums its image's 50 per-box partials + lcn.
__global__ void k_final(const float* __restrict__ pcls, const float* __restrict__ pbox,
                        const float* __restrict__ pcp, const float* __restrict__ lcn,
                        float* __restrict__ out) {
  int lane = threadIdx.x;
  float s = 0.f;
  if (lane < BB) {
    float a = 0.f, bx = 0.f, cp = 0.f;
    for (int i = 0; i < NBOX; ++i) {
      a  += pcls[lane * NBOX + i];
      bx += pbox[lane * NBOX + i];
      cp += pcp[lane * NBOX + i];
    }
    s = (a + bx + cp) / (float)NBOX + lcn[lane];
  }
  #pragma unroll
  for (int off = 32; off > 0; off >>= 1) s += __shfl_down(s, off);
  if (lane == 0) out[0] = s / (float)BB;
}

}  // namespace

extern "C" void kernel_launch(void* const* d_in, const int* in_sizes, int n_in,
                              void* d_out, int out_size, void* d_ws, size_t ws_size,
                              hipStream_t stream) {
  const float* p      = (const float*)d_in[0];
  const float* boxes  = (const float*)d_in[1];
  const int*   labels = (const int*)d_in[2];
  float* out = (float*)d_out;

  char* ws = (char*)d_ws;
  size_t off = 0;
  float4* pltrb = (float4*)(ws + off);             off += (size_t)BB * NT * sizeof(float4);
  unsigned long long* comp = (unsigned long long*)(ws + off); off += (size_t)BB * NT * sizeof(unsigned long long);
  float* pcls = (float*)(ws + off);                off += BB * NBOX * sizeof(float);
  float* pbox = (float*)(ws + off);                off += BB * NBOX * sizeof(float);
  float* pcp  = (float*)(ws + off);                off += BB * NBOX * sizeof(float);
  float* lcn  = (float*)(ws + off);                off += BB * sizeof(float);

  dim3 g1((NT + 255) / 256, BB);
  k_decode_mx<<<g1, 256, 0, stream>>>(p, boxes, pltrb, comp);
  k_neg2<<<BB, 1024, 0, stream>>>(comp, p, lcn);
  k_pos<<<dim3(NBOX, BB), 64, 0, stream>>>(p, boxes, labels, pltrb, pcls, pbox, pcp);
  k_final<<<1, 64, 0, stream>>>(pcls, pbox, pcp, lcn, out);
}

// Round 4
// 82.901 us; speedup vs baseline: 5.8189x; 1.0189x over previous
//
#include <hip/hip_runtime.h>

namespace {

constexpr int BB   = 32;     // batch
constexpr int NBOX = 50;
constexpr int NCLS = 20;
constexpr int NT   = 10647;  // total anchors
constexpr int NNEG = 1000;
constexpr int ANPT = 2;      // anchors per thread in k_decode_mx
constexpr float EPS = 1e-7f;
constexpr float PI4 = (float)(4.0 / 9.869604401089358);  // 4/pi^2

__device__ __constant__ float c_aw[9] = {10.f/416.f,16.f/416.f,33.f/416.f,30.f/416.f,62.f/416.f,59.f/416.f,116.f/416.f,156.f/416.f,373.f/416.f};
__device__ __constant__ float c_ah[9] = {13.f/416.f,30.f/416.f,23.f/416.f,61.f/416.f,45.f/416.f,119.f/416.f,90.f/416.f,198.f/416.f,326.f/416.f};

__device__ __forceinline__ float dciou(float al, float at, float ar, float ab,
                                       float bl, float bt, float br, float bb,
                                       float atanA, float atanB) {
  float ltx = fmaxf(al, bl), lty = fmaxf(at, bt);
  float rbx = fminf(ar, br), rby = fminf(ab, bb);
  float wx = fmaxf(rbx - ltx, 0.f), wy = fmaxf(rby - lty, 0.f);
  float inter = wx * wy;
  float wa = ar - al, ha = ab - at;
  float wb = br - bl, hb = bb - bt;
  float uni = wa * ha + wb * hb - inter;
  float iou = inter / (uni + EPS);
  float cw = fmaxf(ar, br) - fminf(al, bl);
  float ch = fmaxf(ab, bb) - fminf(at, bt);
  float c2 = cw * cw + ch * ch + EPS;
  float dx = (al + ar) * 0.5f - (bl + br) * 0.5f;
  float dy = (at + ab) * 0.5f - (bt + bb) * 0.5f;
  float rho2 = dx * dx + dy * dy;
  float dat = atanA - atanB;
  float v = PI4 * (dat * dat);
  float alpha = v / (1.f - iou + v + EPS);
  return iou - rho2 / c2 - alpha * v;
}

// Hoisted-form CIoU for the decode kernel: A={l,t,r,b}, E={cx,cy,atanA}.
// Per-anchor values (wb,hb,cxb,cyb,atanB) precomputed once; expression
// shapes match dciou exactly (same rounding / contraction opportunities).
__device__ __forceinline__ float dciou_h(float4 A, float4 E,
                                         float bl, float bt, float br, float bb,
                                         float wb, float hb,
                                         float cxb, float cyb, float atanB) {
  float al = A.x, at = A.y, ar = A.z, ab = A.w;
  float ltx = fmaxf(al, bl), lty = fmaxf(at, bt);
  float rbx = fminf(ar, br), rby = fminf(ab, bb);
  float wx = fmaxf(rbx - ltx, 0.f), wy = fmaxf(rby - lty, 0.f);
  float inter = wx * wy;
  float wa = ar - al, ha = ab - at;
  float uni = wa * ha + wb * hb - inter;
  float iou = inter / (uni + EPS);
  float cw = fmaxf(ar, br) - fminf(al, bl);
  float ch = fmaxf(ab, bb) - fminf(at, bt);
  float c2 = cw * cw + ch * ch + EPS;
  float dx = E.x - cxb;
  float dy = E.y - cyb;
  float rho2 = dx * dx + dy * dy;
  float dat = E.z - atanB;
  float v = PI4 * (dat * dat);
  float alpha = v / (1.f - iou + v + EPS);
  return iou - rho2 / c2 - alpha * v;
}

__device__ __forceinline__ int wave_incl_scan(int x, int lane) {
  #pragma unroll
  for (int off = 1; off < 64; off <<= 1) {
    int y = __shfl_up(x, off);
    if (lane >= off) x += y;
  }
  return x;
}

// K1: decode pred boxes -> pltrb; mx over 50 GT boxes; composite sort key.
// 2 anchors/thread; box data staged as float4 LDS tiles.
__global__ __launch_bounds__(256) void k_decode_mx(const float* __restrict__ p, const float* __restrict__ boxes,
                            float4* __restrict__ pltrb, unsigned long long* __restrict__ comp) {
  const int b = blockIdx.y;
  const int tid = threadIdx.x;
  const int base = blockIdx.x * (256 * ANPT);

  __shared__ float4 sA[NBOX];   // l,t,r,b
  __shared__ float4 sE[NBOX];   // cx,cy,atanA,0
  if (tid < NBOX) {
    const float* bp = boxes + (b * NBOX + tid) * 4;
    float l = bp[0], t = bp[1], r = bp[2], d = bp[3];
    sA[tid] = make_float4(l, t, r, d);
    float wa = r - l, ha = d - t;
    float cx = (l + r) * 0.5f, cy = (t + d) * 0.5f;
    sE[tid] = make_float4(cx, cy, atanf(wa / (ha + EPS)), 0.f);
  }
  __syncthreads();

  float bl[ANPT], bt[ANPT], br[ANPT], bbv[ANPT];
  float wbv[ANPT], hbv[ANPT], cxb[ANPT], cyb[ANPT], atb[ANPT];
  float mx[ANPT];
  int jv[ANPT];
  bool act[ANPT];

  #pragma unroll
  for (int s = 0; s < ANPT; ++s) {
    int j = base + s * 256 + tid;
    jv[s] = j;
    act[s] = (j < NT);
    mx[s] = -INFINITY;
    if (!act[s]) continue;
    int lvl, jb0, f;
    if (j < 8112)       { lvl = 0; jb0 = 0;     f = 52; }
    else if (j < 10140) { lvl = 1; jb0 = 8112;  f = 26; }
    else                { lvl = 2; jb0 = 10140; f = 13; }
    int jj = j - jb0;
    int cell = jj / 3, a = jj % 3 + lvl * 3;
    int x = cell % f, y = cell / f;
    float ff = (float)f;
    const float* pr = p + ((size_t)b * NT + j) * 25;
    float px = pr[0] / ff + (float)x / ff;
    float py = pr[1] / ff + (float)y / ff;
    float pw = expf(pr[2]) * c_aw[a];
    float ph = expf(pr[3]) * c_ah[a];
    float l = px - pw * 0.5f, t = py - ph * 0.5f;
    float r = px + pw * 0.5f, d = py + ph * 0.5f;
    pltrb[(size_t)b * NT + j] = make_float4(l, t, r, d);
    bl[s] = l; bt[s] = t; br[s] = r; bbv[s] = d;
    wbv[s] = r - l; hbv[s] = d - t;
    cxb[s] = (l + r) * 0.5f; cyb[s] = (t + d) * 0.5f;
    atb[s] = atanf(wbv[s] / (hbv[s] + EPS));
  }

  for (int i = 0; i < NBOX; ++i) {
    float4 A = sA[i];
    float4 E = sE[i];
    #pragma unroll
    for (int s = 0; s < ANPT; ++s) {
      float v = dciou_h(A, E, bl[s], bt[s], br[s], bbv[s], wbv[s], hbv[s], cxb[s], cyb[s], atb[s]);
      mx[s] = fmaxf(mx[s], v);
    }
  }

  #pragma unroll
  for (int s = 0; s < ANPT; ++s) {
    if (!act[s]) continue;
    float key = (mx[s] < 0.5f) ? mx[s] : INFINITY;
    unsigned int u = __float_as_uint(key);
    u = (u & 0x80000000u) ? ~u : (u | 0x80000000u);
    comp[(size_t)b * NT + jv[s]] = ((unsigned long long)u << 14) | (unsigned long long)jv[s];
  }
}

// K2 (fused select + scan + BCE): per-image 4-pass radix-histogram select of the
// 999th-smallest composite; then a fused cumsum(mask)-1 block scan over j to get
// the rank index used as the p-row (ref quirk), accumulating l_conf_n.
__global__ __launch_bounds__(1024) void k_neg2(const unsigned long long* __restrict__ comp,
                                               const float* __restrict__ p,
                                               float* __restrict__ lcn) {
  int b = blockIdx.x;
  const unsigned long long* c = comp + (size_t)b * NT;
  const int tid = threadIdx.x, lane = tid & 63, wave = tid >> 6;

  __shared__ int hist[4096];
  __shared__ int s_w[16];
  __shared__ unsigned long long s_pref;
  __shared__ int s_rem;
  __shared__ int s_carry;
  __shared__ int s_digit;
  __shared__ int s_rem_next;
  __shared__ float s_facc[16];

  // Hoist the image's composites into registers: 11 per thread (chunk-major).
  unsigned long long v[11];
  #pragma unroll
  for (int k = 0; k < 11; ++k) {
    int j = k * 1024 + tid;
    v[k] = (j < NT) ? c[j] : ~0ull;   // pad > any 46-bit composite; excluded by prefix check
  }

  if (tid == 0) { s_pref = 0ull; s_rem = NNEG - 1; s_carry = 0; }
  __syncthreads();

  // 4 radix passes over digit windows [47:36],[35:24],[23:12],[11:0].
  for (int pass = 0; pass < 4; ++pass) {
    int lo = 36 - pass * 12;
    for (int h = tid; h < 4096; h += 1024) hist[h] = 0;
    __syncthreads();
    unsigned long long pref = s_pref;
    #pragma unroll
    for (int k = 0; k < 11; ++k) {
      unsigned long long x = v[k];
      if ((x >> (lo + 12)) == (pref >> (lo + 12)))
        atomicAdd(&hist[(int)((x >> lo) & 4095ull)], 1);
    }
    __syncthreads();
    // Block-wide exclusive scan over 4096 buckets (4 per thread), locate target.
    int base = tid * 4;
    int c0 = hist[base], c1 = hist[base + 1], c2 = hist[base + 2], c3 = hist[base + 3];
    int tsum = c0 + c1 + c2 + c3;
    int incl = wave_incl_scan(tsum, lane);
    if (lane == 63) s_w[wave] = incl;
    __syncthreads();
    if (wave == 0) {
      int wv = (lane < 16) ? s_w[lane] : 0;
      int wincl = wave_incl_scan(wv, lane);
      if (lane < 16) s_w[lane] = wincl - wv;  // exclusive wave offsets
    }
    __syncthreads();
    int excl = incl - tsum + s_w[wave];
    int rem = s_rem;
    int p0 = excl, p1 = p0 + c0, p2 = p1 + c1, p3 = p2 + c2;
    if (rem >= p0 && rem < p0 + c0) { s_digit = base + 0; s_rem_next = rem - p0; }
    if (rem >= p1 && rem < p1 + c1) { s_digit = base + 1; s_rem_next = rem - p1; }
    if (rem >= p2 && rem < p2 + c2) { s_digit = base + 2; s_rem_next = rem - p2; }
    if (rem >= p3 && rem < p3 + c3) { s_digit = base + 3; s_rem_next = rem - p3; }
    __syncthreads();
    if (tid == 0) {
      s_pref |= ((unsigned long long)s_digit) << lo;
      s_rem = s_rem_next;
    }
    __syncthreads();
  }
  const unsigned long long T = s_pref;  // exact 999th-smallest composite (unique keys)

  // Fused scan (rank = cumsum(mask)-1) + selection (c<=T) + BCE accumulate.
  float acc = 0.f;
  const float* pb = p + (size_t)b * NT * 25;
  #pragma unroll
  for (int k = 0; k < 11; ++k) {
    unsigned long long x = v[k];
    int flag = ((x >> 14) < 0xFF800000ull) ? 1 : 0;  // finite ordkey => masked
    int incl = wave_incl_scan(flag, lane);
    if (lane == 63) s_w[wave] = incl;
    __syncthreads();
    if (wave == 0) {
      int wv = (lane < 16) ? s_w[lane] : 0;
      int wincl = wave_incl_scan(wv, lane);
      if (lane < 16) s_w[lane] = wincl - wv;
    }
    __syncthreads();
    int rank = s_carry + s_w[wave] + incl - 1;
    if (x <= T) {
      int idx = rank;
      if (idx < 0) idx += NT;  // JAX negative-index wrap (rank can be -1)
      float q = 1.f - pb[(size_t)idx * 25 + 4];
      q = fminf(fmaxf(q, EPS), 1.f - EPS);
      acc += -logf(q);
    }
    __syncthreads();
    if (tid == 1023) s_carry += s_w[15] + incl;  // chunk total
    __syncthreads();
  }

  // Reduce acc across the block.
  #pragma unroll
  for (int off = 32; off > 0; off >>= 1) acc += __shfl_down(acc, off);
  if (lane == 0) s_facc[wave] = acc;
  __syncthreads();
  if (tid == 0) {
    float s = 0.f;
    #pragma unroll
    for (int w = 0; w < 16; ++w) s += s_facc[w];
    lcn[b] = s;
  }
}

// K3: positive losses. One wave per (image, box): grid (NBOX, BB) x 64 threads.
__global__ __launch_bounds__(64) void k_pos(const float* __restrict__ p, const float* __restrict__ boxes,
                      const int* __restrict__ labels, const float4* __restrict__ pltrb,
                      float* __restrict__ pcls, float* __restrict__ pbox, float* __restrict__ pcp) {
  const int i = blockIdx.x;       // box
  const int b = blockIdx.y;       // image
  const int lane = threadIdx.x;   // 0..63

  __shared__ float scx[NBOX], scy[NBOX];
  if (lane < NBOX) {
    const float* bp = boxes + (b * NBOX + lane) * 4;
    float l = bp[0], t = bp[1], r = bp[2], d = bp[3];
    scx[lane] = (l + r) * 0.5f;
    scy[lane] = (t + d) * 0.5f;
  }
  __syncthreads();

  const float* bi = boxes + (b * NBOX + i) * 4;
  float bl0 = bi[0], bt0 = bi[1], br0 = bi[2], bd0 = bi[3];
  float fi = (float)i;
  float al = bl0 + fi, at = bt0 + fi, ar = br0 + fi, ad = bd0 + fi;
  float wa = ar - al, ha = ad - at;
  float atanA = atanf(wa / (ha + EPS));

  float bestv = -INFINITY; int bestm = 1 << 30;
  #pragma unroll
  for (int m = lane; m < 9 * NBOX; m += 64) {
    int jb = m / 9, a = m % 9;
    float fa = (a < 3) ? 52.f : (a < 6 ? 26.f : 13.f);
    float col = floorf(scx[jb] * fa);
    float row = floorf(scy[jb] * fa);
    float ax = col / fa, ay = row / fa;
    float aw = c_aw[a], ah = c_ah[a];
    float fj = (float)jb;
    float bl = (ax - aw * 0.5f) + fj;
    float bt = (ay - ah * 0.5f) + fj;
    float br = (ax + aw * 0.5f) + fj;
    float bd = (ay + ah * 0.5f) + fj;
    float wb = br - bl, hb = bd - bt;
    float atanB = atanf(wb / (hb + EPS));
    float v = dciou(al, at, ar, ad, bl, bt, br, bd, atanA, atanB);
    if (v > bestv) { bestv = v; bestm = m; }
  }
  #pragma unroll
  for (int off = 32; off > 0; off >>= 1) {
    float ov = __shfl_down(bestv, off);
    int om = __shfl_down(bestm, off);
    if (ov > bestv || (ov == bestv && om < bestm)) { bestv = ov; bestm = om; }
  }
  int bm = __shfl(bestm, 0);

  int k = bm % 9;
  int lvl = k / 3;
  float fk = (k < 3) ? 52.f : (k < 6 ? 26.f : 13.f);
  float col = floorf(scx[i] * fk);
  float row = floorf(scy[i] * fk);
  float offc = (lvl == 0) ? 0.f : (lvl == 1 ? 2704.f : 3380.f);
  int midx = (int)((offc + row * fk + col) * 3.0f + (float)lvl);  // ref uses +lvl, not +k%3

  const float* pr = p + ((size_t)b * NT + midx) * 25;
  int lab = labels[b * NBOX + i] - 1;

  float lc = 0.f;
  if (lane < NCLS) {
    float pc = pr[5 + lane];
    pc = fminf(fmaxf(pc, EPS), 1.f - EPS);
    float tt = (lane == lab) ? 1.f : 0.f;
    lc = -(tt * logf(pc) + (1.f - tt) * logf(1.f - pc));
  }
  #pragma unroll
  for (int off = 32; off > 0; off >>= 1) lc += __shfl_down(lc, off);

  if (lane == 0) {
    pcls[b * NBOX + i] = lc;
    float pc4 = pr[4];
    pc4 = fminf(fmaxf(pc4, EPS), 1.f - EPS);
    pcp[b * NBOX + i] = -logf(pc4);
    float4 pb4 = pltrb[(size_t)b * NT + midx];
    float wb = pb4.z - pb4.x, hb = pb4.w - pb4.y;
    float atanB = atanf(wb / (hb + EPS));
    float wa0 = br0 - bl0, ha0 = bd0 - bt0;
    float atanA0 = atanf(wa0 / (ha0 + EPS));
    float cp = dciou(bl0, bt0, br0, bd0, pb4.x, pb4.y, pb4.z, pb4.w, atanA0, atanB);
    float w = 2.f - wa0 * ha0;
    pbox[b * NBOX + i] = w * (1.f - cp);
  }
}

// K4: final reduce. Lane b (<32) sums its image's 50 per-box partials + lcn.
__global__ void k_final(const float* __restrict__ pcls, const float* __restrict__ pbox,
                        const float* __restrict__ pcp, const float* __restrict__ lcn,
                        float* __restrict__ out) {
  int lane = threadIdx.x;
  float s = 0.f;
  if (lane < BB) {
    float a = 0.f, bx = 0.f, cp = 0.f;
    for (int i = 0; i < NBOX; ++i) {
      a  += pcls[lane * NBOX + i];
      bx += pbox[lane * NBOX + i];
      cp += pcp[lane * NBOX + i];
    }
    s = (a + bx + cp) / (float)NBOX + lcn[lane];
  }
  #pragma unroll
  for (int off = 32; off > 0; off >>= 1) s += __shfl_down(s, off);
  if (lane == 0) out[0] = s / (float)BB;
}

}  // namespace

extern "C" void kernel_launch(void* const* d_in, const int* in_sizes, int n_in,
                              void* d_out, int out_size, void* d_ws, size_t ws_size,
                              hipStream_t stream) {
  const float* p      = (const float*)d_in[0];
  const float* boxes  = (const float*)d_in[1];
  const int*   labels = (const int*)d_in[2];
  float* out = (float*)d_out;

  char* ws = (char*)d_ws;
  size_t off = 0;
  float4* pltrb = (float4*)(ws + off);             off += (size_t)BB * NT * sizeof(float4);
  unsigned long long* comp = (unsigned long long*)(ws + off); off += (size_t)BB * NT * sizeof(unsigned long long);
  float* pcls = (float*)(ws + off);                off += BB * NBOX * sizeof(float);
  float* pbox = (float*)(ws + off);                off += BB * NBOX * sizeof(float);
  float* pcp  = (float*)(ws + off);                off += BB * NBOX * sizeof(float);
  float* lcn  = (float*)(ws + off);                off += BB * sizeof(float);

  dim3 g1((NT + 256 * ANPT - 1) / (256 * ANPT), BB);
  k_decode_mx<<<g1, 256, 0, stream>>>(p, boxes, pltrb, comp);
  k_neg2<<<BB, 1024, 0, stream>>>(comp, p, lcn);
  k_pos<<<dim3(NBOX, BB), 64, 0, stream>>>(p, boxes, labels, pltrb, pcls, pbox, pcp);
  k_final<<<1, 64, 0, stream>>>(pcls, pbox, pcp, lcn, out);
}

// Round 5
// 72.835 us; speedup vs baseline: 6.6230x; 1.1382x over previous
//
#include <hip/hip_runtime.h>

namespace {

constexpr int BB   = 32;     // batch
constexpr int NBOX = 50;
constexpr int NCLS = 20;
constexpr int NT   = 10647;  // total anchors
constexpr int NNEG = 1000;
constexpr int ANPT = 2;      // anchors per thread in k_decode_mx
constexpr float EPS = 1e-7f;
constexpr float PI4 = (float)(4.0 / 9.869604401089358);  // 4/pi^2

__device__ __constant__ float c_aw[9] = {10.f/416.f,16.f/416.f,33.f/416.f,30.f/416.f,62.f/416.f,59.f/416.f,116.f/416.f,156.f/416.f,373.f/416.f};
__device__ __constant__ float c_ah[9] = {13.f/416.f,30.f/416.f,23.f/416.f,61.f/416.f,45.f/416.f,119.f/416.f,90.f/416.f,198.f/416.f,326.f/416.f};

// rcp + 1 Newton-Raphson step: ~1ulp, no VCC (v_div_scale/v_div_fmas) serialization.
__device__ __forceinline__ float fastrcp(float x) {
  float r = __builtin_amdgcn_rcpf(x);
  r = fmaf(fmaf(-x, r, 1.f), r, r);
  return r;
}

__device__ __forceinline__ float dciou(float al, float at, float ar, float ab,
                                       float bl, float bt, float br, float bb,
                                       float atanA, float atanB) {
  float ltx = fmaxf(al, bl), lty = fmaxf(at, bt);
  float rbx = fminf(ar, br), rby = fminf(ab, bb);
  float wx = fmaxf(rbx - ltx, 0.f), wy = fmaxf(rby - lty, 0.f);
  float inter = wx * wy;
  float wa = ar - al, ha = ab - at;
  float wb = br - bl, hb = bb - bt;
  float uni = wa * ha + wb * hb - inter;
  float iou = inter / (uni + EPS);
  float cw = fmaxf(ar, br) - fminf(al, bl);
  float ch = fmaxf(ab, bb) - fminf(at, bt);
  float c2 = cw * cw + ch * ch + EPS;
  float dx = (al + ar) * 0.5f - (bl + br) * 0.5f;
  float dy = (at + ab) * 0.5f - (bt + bb) * 0.5f;
  float rho2 = dx * dx + dy * dy;
  float dat = atanA - atanB;
  float v = PI4 * (dat * dat);
  float alpha = v / (1.f - iou + v + EPS);
  return iou - rho2 / c2 - alpha * v;
}

// Decode-path CIoU: A={l,t,r,b}, E={cx,cy,atanA,areaA}; per-anchor values
// (areaB,cxb,cyb,atanB) hoisted; divisions via fastrcp (no VCC contention).
__device__ __forceinline__ float dciou_h(float4 A, float4 E,
                                         float bl, float bt, float br, float bb,
                                         float areaB,
                                         float cxb, float cyb, float atanB) {
  float ltx = fmaxf(A.x, bl), lty = fmaxf(A.y, bt);
  float rbx = fminf(A.z, br), rby = fminf(A.w, bb);
  float wx = fmaxf(rbx - ltx, 0.f), wy = fmaxf(rby - lty, 0.f);
  float inter = wx * wy;
  float uni = E.w + areaB - inter;
  float iou = inter * fastrcp(uni + EPS);
  float cw = fmaxf(A.z, br) - fminf(A.x, bl);
  float ch = fmaxf(A.w, bb) - fminf(A.y, bt);
  float c2 = cw * cw + ch * ch + EPS;
  float dx = E.x - cxb;
  float dy = E.y - cyb;
  float rho2 = dx * dx + dy * dy;
  float dat = E.z - atanB;
  float v = PI4 * (dat * dat);
  float alpha = v * fastrcp(1.f - iou + v + EPS);
  return iou - rho2 * fastrcp(c2) - alpha * v;
}

__device__ __forceinline__ int wave_incl_scan(int x, int lane) {
  #pragma unroll
  for (int off = 1; off < 64; off <<= 1) {
    int y = __shfl_up(x, off);
    if (lane >= off) x += y;
  }
  return x;
}

// K1: decode pred boxes -> pltrb; mx over 50 GT boxes; composite sort key.
__global__ __launch_bounds__(256) void k_decode_mx(const float* __restrict__ p, const float* __restrict__ boxes,
                            float4* __restrict__ pltrb, unsigned long long* __restrict__ comp) {
  const int b = blockIdx.y;
  const int tid = threadIdx.x;
  const int base = blockIdx.x * (256 * ANPT);

  __shared__ float4 sA[NBOX];   // l,t,r,b
  __shared__ float4 sE[NBOX];   // cx,cy,atanA,areaA
  if (tid < NBOX) {
    const float* bp = boxes + (b * NBOX + tid) * 4;
    float l = bp[0], t = bp[1], r = bp[2], d = bp[3];
    sA[tid] = make_float4(l, t, r, d);
    float wa = r - l, ha = d - t;
    float cx = (l + r) * 0.5f, cy = (t + d) * 0.5f;
    sE[tid] = make_float4(cx, cy, atanf(wa / (ha + EPS)), wa * ha);
  }
  __syncthreads();

  float bl[ANPT], bt[ANPT], br[ANPT], bbv[ANPT];
  float areab[ANPT], cxb[ANPT], cyb[ANPT], atb[ANPT];
  float mx[ANPT];
  int jv[ANPT];
  bool act[ANPT];

  #pragma unroll
  for (int s = 0; s < ANPT; ++s) {
    int j = base + s * 256 + tid;
    jv[s] = j;
    act[s] = (j < NT);
    mx[s] = -INFINITY;
    if (!act[s]) continue;
    int lvl, jb0, f;
    if (j < 8112)       { lvl = 0; jb0 = 0;     f = 52; }
    else if (j < 10140) { lvl = 1; jb0 = 8112;  f = 26; }
    else                { lvl = 2; jb0 = 10140; f = 13; }
    int jj = j - jb0;
    int cell = jj / 3, a = jj % 3 + lvl * 3;
    int x = cell % f, y = cell / f;
    float ff = (float)f;
    const float* pr = p + ((size_t)b * NT + j) * 25;
    float px = pr[0] / ff + (float)x / ff;
    float py = pr[1] / ff + (float)y / ff;
    float pw = expf(pr[2]) * c_aw[a];
    float ph = expf(pr[3]) * c_ah[a];
    float l = px - pw * 0.5f, t = py - ph * 0.5f;
    float r = px + pw * 0.5f, d = py + ph * 0.5f;
    pltrb[(size_t)b * NT + j] = make_float4(l, t, r, d);
    bl[s] = l; bt[s] = t; br[s] = r; bbv[s] = d;
    float wb = r - l, hb = d - t;
    areab[s] = wb * hb;
    cxb[s] = (l + r) * 0.5f; cyb[s] = (t + d) * 0.5f;
    atb[s] = atanf(wb / (hb + EPS));
  }

  for (int i = 0; i < NBOX; ++i) {
    float4 A = sA[i];
    float4 E = sE[i];
    #pragma unroll
    for (int s = 0; s < ANPT; ++s) {
      float v = dciou_h(A, E, bl[s], bt[s], br[s], bbv[s], areab[s], cxb[s], cyb[s], atb[s]);
      mx[s] = fmaxf(mx[s], v);
    }
  }

  #pragma unroll
  for (int s = 0; s < ANPT; ++s) {
    if (!act[s]) continue;
    float key = (mx[s] < 0.5f) ? mx[s] : INFINITY;
    unsigned int u = __float_as_uint(key);
    u = (u & 0x80000000u) ? ~u : (u | 0x80000000u);
    comp[(size_t)b * NT + jv[s]] = ((unsigned long long)u << 14) | (unsigned long long)jv[s];
  }
}

// K2 (fused select + scan + BCE): per-image 4-pass radix-histogram select of the
// 999th-smallest composite; then a fused cumsum(mask)-1 block scan over j to get
// the rank index used as the p-row (ref quirk), accumulating l_conf_n.
__global__ __launch_bounds__(1024) void k_neg2(const unsigned long long* __restrict__ comp,
                                               const float* __restrict__ p,
                                               float* __restrict__ lcn) {
  int b = blockIdx.x;
  const unsigned long long* c = comp + (size_t)b * NT;
  const int tid = threadIdx.x, lane = tid & 63, wave = tid >> 6;

  __shared__ int hist[4096];
  __shared__ int s_w[16];
  __shared__ unsigned long long s_pref;
  __shared__ int s_rem;
  __shared__ int s_carry;
  __shared__ int s_digit;
  __shared__ int s_rem_next;
  __shared__ float s_facc[16];

  // Hoist the image's composites into registers: 11 per thread (chunk-major).
  unsigned long long v[11];
  #pragma unroll
  for (int k = 0; k < 11; ++k) {
    int j = k * 1024 + tid;
    v[k] = (j < NT) ? c[j] : ~0ull;   // pad > any 46-bit composite; excluded by prefix check
  }

  if (tid == 0) { s_pref = 0ull; s_rem = NNEG - 1; s_carry = 0; }
  __syncthreads();

  // 4 radix passes over digit windows [47:36],[35:24],[23:12],[11:0].
  for (int pass = 0; pass < 4; ++pass) {
    int lo = 36 - pass * 12;
    for (int h = tid; h < 4096; h += 1024) hist[h] = 0;
    __syncthreads();
    unsigned long long pref = s_pref;
    #pragma unroll
    for (int k = 0; k < 11; ++k) {
      unsigned long long x = v[k];
      if ((x >> (lo + 12)) == (pref >> (lo + 12)))
        atomicAdd(&hist[(int)((x >> lo) & 4095ull)], 1);
    }
    __syncthreads();
    // Block-wide exclusive scan over 4096 buckets (4 per thread), locate target.
    int base = tid * 4;
    int c0 = hist[base], c1 = hist[base + 1], c2 = hist[base + 2], c3 = hist[base + 3];
    int tsum = c0 + c1 + c2 + c3;
    int incl = wave_incl_scan(tsum, lane);
    if (lane == 63) s_w[wave] = incl;
    __syncthreads();
    if (wave == 0) {
      int wv = (lane < 16) ? s_w[lane] : 0;
      int wincl = wave_incl_scan(wv, lane);
      if (lane < 16) s_w[lane] = wincl - wv;  // exclusive wave offsets
    }
    __syncthreads();
    int excl = incl - tsum + s_w[wave];
    int rem = s_rem;
    int p0 = excl, p1 = p0 + c0, p2 = p1 + c1, p3 = p2 + c2;
    if (rem >= p0 && rem < p0 + c0) { s_digit = base + 0; s_rem_next = rem - p0; }
    if (rem >= p1 && rem < p1 + c1) { s_digit = base + 1; s_rem_next = rem - p1; }
    if (rem >= p2 && rem < p2 + c2) { s_digit = base + 2; s_rem_next = rem - p2; }
    if (rem >= p3 && rem < p3 + c3) { s_digit = base + 3; s_rem_next = rem - p3; }
    __syncthreads();
    if (tid == 0) {
      s_pref |= ((unsigned long long)s_digit) << lo;
      s_rem = s_rem_next;
    }
    __syncthreads();
  }
  const unsigned long long T = s_pref;  // exact 999th-smallest composite (unique keys)

  // Fused scan (rank = cumsum(mask)-1) + selection (c<=T) + BCE accumulate.
  float acc = 0.f;
  const float* pb = p + (size_t)b * NT * 25;
  #pragma unroll
  for (int k = 0; k < 11; ++k) {
    unsigned long long x = v[k];
    int flag = ((x >> 14) < 0xFF800000ull) ? 1 : 0;  // finite ordkey => masked
    int incl = wave_incl_scan(flag, lane);
    if (lane == 63) s_w[wave] = incl;
    __syncthreads();
    if (wave == 0) {
      int wv = (lane < 16) ? s_w[lane] : 0;
      int wincl = wave_incl_scan(wv, lane);
      if (lane < 16) s_w[lane] = wincl - wv;
    }
    __syncthreads();
    int rank = s_carry + s_w[wave] + incl - 1;
    if (x <= T) {
      int idx = rank;
      if (idx < 0) idx += NT;  // JAX negative-index wrap (rank can be -1)
      float q = 1.f - pb[(size_t)idx * 25 + 4];
      q = fminf(fmaxf(q, EPS), 1.f - EPS);
      acc += -logf(q);
    }
    __syncthreads();
    if (tid == 1023) s_carry += s_w[15] + incl;  // chunk total
    __syncthreads();
  }

  // Reduce acc across the block.
  #pragma unroll
  for (int off = 32; off > 0; off >>= 1) acc += __shfl_down(acc, off);
  if (lane == 0) s_facc[wave] = acc;
  __syncthreads();
  if (tid == 0) {
    float s = 0.f;
    #pragma unroll
    for (int w = 0; w < 16; ++w) s += s_facc[w];
    lcn[b] = s;
  }
}

// K3: positive losses. One wave per (image, box): grid (NBOX, BB) x 64 threads.
__global__ __launch_bounds__(64) void k_pos(const float* __restrict__ p, const float* __restrict__ boxes,
                      const int* __restrict__ labels, const float4* __restrict__ pltrb,
                      float* __restrict__ pcls, float* __restrict__ pbox, float* __restrict__ pcp) {
  const int i = blockIdx.x;       // box
  const int b = blockIdx.y;       // image
  const int lane = threadIdx.x;   // 0..63

  __shared__ float scx[NBOX], scy[NBOX];
  if (lane < NBOX) {
    const float* bp = boxes + (b * NBOX + lane) * 4;
    float l = bp[0], t = bp[1], r = bp[2], d = bp[3];
    scx[lane] = (l + r) * 0.5f;
    scy[lane] = (t + d) * 0.5f;
  }
  __syncthreads();

  const float* bi = boxes + (b * NBOX + i) * 4;
  float bl0 = bi[0], bt0 = bi[1], br0 = bi[2], bd0 = bi[3];
  float fi = (float)i;
  float al = bl0 + fi, at = bt0 + fi, ar = br0 + fi, ad = bd0 + fi;
  float wa = ar - al, ha = ad - at;
  float atanA = atanf(wa / (ha + EPS));

  float bestv = -INFINITY; int bestm = 1 << 30;
  #pragma unroll
  for (int m = lane; m < 9 * NBOX; m += 64) {
    int jb = m / 9, a = m % 9;
    float fa = (a < 3) ? 52.f : (a < 6 ? 26.f : 13.f);
    float col = floorf(scx[jb] * fa);
    float row = floorf(scy[jb] * fa);
    float ax = col / fa, ay = row / fa;
    float aw = c_aw[a], ah = c_ah[a];
    float fj = (float)jb;
    float bl = (ax - aw * 0.5f) + fj;
    float bt = (ay - ah * 0.5f) + fj;
    float br = (ax + aw * 0.5f) + fj;
    float bd = (ay + ah * 0.5f) + fj;
    float wb = br - bl, hb = bd - bt;
    float atanB = atanf(wb / (hb + EPS));
    float v = dciou(al, at, ar, ad, bl, bt, br, bd, atanA, atanB);
    if (v > bestv) { bestv = v; bestm = m; }
  }
  #pragma unroll
  for (int off = 32; off > 0; off >>= 1) {
    float ov = __shfl_down(bestv, off);
    int om = __shfl_down(bestm, off);
    if (ov > bestv || (ov == bestv && om < bestm)) { bestv = ov; bestm = om; }
  }
  int bm = __shfl(bestm, 0);

  int k = bm % 9;
  int lvl = k / 3;
  float fk = (k < 3) ? 52.f : (k < 6 ? 26.f : 13.f);
  float col = floorf(scx[i] * fk);
  float row = floorf(scy[i] * fk);
  float offc = (lvl == 0) ? 0.f : (lvl == 1 ? 2704.f : 3380.f);
  int midx = (int)((offc + row * fk + col) * 3.0f + (float)lvl);  // ref uses +lvl, not +k%3

  const float* pr = p + ((size_t)b * NT + midx) * 25;
  int lab = labels[b * NBOX + i] - 1;

  float lc = 0.f;
  if (lane < NCLS) {
    float pc = pr[5 + lane];
    pc = fminf(fmaxf(pc, EPS), 1.f - EPS);
    float tt = (lane == lab) ? 1.f : 0.f;
    lc = -(tt * logf(pc) + (1.f - tt) * logf(1.f - pc));
  }
  #pragma unroll
  for (int off = 32; off > 0; off >>= 1) lc += __shfl_down(lc, off);

  if (lane == 0) {
    pcls[b * NBOX + i] = lc;
    float pc4 = pr[4];
    pc4 = fminf(fmaxf(pc4, EPS), 1.f - EPS);
    pcp[b * NBOX + i] = -logf(pc4);
    float4 pb4 = pltrb[(size_t)b * NT + midx];
    float wb = pb4.z - pb4.x, hb = pb4.w - pb4.y;
    float atanB = atanf(wb / (hb + EPS));
    float wa0 = br0 - bl0, ha0 = bd0 - bt0;
    float atanA0 = atanf(wa0 / (ha0 + EPS));
    float cp = dciou(bl0, bt0, br0, bd0, pb4.x, pb4.y, pb4.z, pb4.w, atanA0, atanB);
    float w = 2.f - wa0 * ha0;
    pbox[b * NBOX + i] = w * (1.f - cp);
  }
}

// K4: final reduce. Lane b (<32) sums its image's 50 per-box partials + lcn.
__global__ void k_final(const float* __restrict__ pcls, const float* __restrict__ pbox,
                        const float* __restrict__ pcp, const float* __restrict__ lcn,
                        float* __restrict__ out) {
  int lane = threadIdx.x;
  float s = 0.f;
  if (lane < BB) {
    float a = 0.f, bx = 0.f, cp = 0.f;
    for (int i = 0; i < NBOX; ++i) {
      a  += pcls[lane * NBOX + i];
      bx += pbox[lane * NBOX + i];
      cp += pcp[lane * NBOX + i];
    }
    s = (a + bx + cp) / (float)NBOX + lcn[lane];
  }
  #pragma unroll
  for (int off = 32; off > 0; off >>= 1) s += __shfl_down(s, off);
  if (lane == 0) out[0] = s / (float)BB;
}

}  // namespace

extern "C" void kernel_launch(void* const* d_in, const int* in_sizes, int n_in,
                              void* d_out, int out_size, void* d_ws, size_t ws_size,
                              hipStream_t stream) {
  const float* p      = (const float*)d_in[0];
  const float* boxes  = (const float*)d_in[1];
  const int*   labels = (const int*)d_in[2];
  float* out = (float*)d_out;

  char* ws = (char*)d_ws;
  size_t off = 0;
  float4* pltrb = (float4*)(ws + off);             off += (size_t)BB * NT * sizeof(float4);
  unsigned long long* comp = (unsigned long long*)(ws + off); off += (size_t)BB * NT * sizeof(unsigned long long);
  float* pcls = (float*)(ws + off);                off += BB * NBOX * sizeof(float);
  float* pbox = (float*)(ws + off);                off += BB * NBOX * sizeof(float);
  float* pcp  = (float*)(ws + off);                off += BB * NBOX * sizeof(float);
  float* lcn  = (float*)(ws + off);                off += BB * sizeof(float);

  dim3 g1((NT + 256 * ANPT - 1) / (256 * ANPT), BB);
  k_decode_mx<<<g1, 256, 0, stream>>>(p, boxes, pltrb, comp);
  k_neg2<<<BB, 1024, 0, stream>>>(comp, p, lcn);
  k_pos<<<dim3(NBOX, BB), 64, 0, stream>>>(p, boxes, labels, pltrb, pcls, pbox, pcp);
  k_final<<<1, 64, 0, stream>>>(pcls, pbox, pcp, lcn, out);
}

// Round 6
// 70.855 us; speedup vs baseline: 6.8082x; 1.0280x over previous
//
#include <hip/hip_runtime.h>

namespace {

constexpr int BB   = 32;     // batch
constexpr int NBOX = 50;
constexpr int NCLS = 20;
constexpr int NT   = 10647;  // total anchors
constexpr int NNEG = 1000;
constexpr float EPS = 1e-7f;
constexpr float PI4 = (float)(4.0 / 9.869604401089358);  // 4/pi^2

__device__ __constant__ float c_aw[9] = {10.f/416.f,16.f/416.f,33.f/416.f,30.f/416.f,62.f/416.f,59.f/416.f,116.f/416.f,156.f/416.f,373.f/416.f};
__device__ __constant__ float c_ah[9] = {13.f/416.f,30.f/416.f,23.f/416.f,61.f/416.f,45.f/416.f,119.f/416.f,90.f/416.f,198.f/416.f,326.f/416.f};

// rcp + 1 Newton-Raphson step: ~1ulp, no VCC (v_div_scale/v_div_fmas) serialization.
__device__ __forceinline__ float fastrcp(float x) {
  float r = __builtin_amdgcn_rcpf(x);
  r = fmaf(fmaf(-x, r, 1.f), r, r);
  return r;
}

__device__ __forceinline__ float dciou(float al, float at, float ar, float ab,
                                       float bl, float bt, float br, float bb,
                                       float atanA, float atanB) {
  float ltx = fmaxf(al, bl), lty = fmaxf(at, bt);
  float rbx = fminf(ar, br), rby = fminf(ab, bb);
  float wx = fmaxf(rbx - ltx, 0.f), wy = fmaxf(rby - lty, 0.f);
  float inter = wx * wy;
  float wa = ar - al, ha = ab - at;
  float wb = br - bl, hb = bb - bt;
  float uni = wa * ha + wb * hb - inter;
  float iou = inter / (uni + EPS);
  float cw = fmaxf(ar, br) - fminf(al, bl);
  float ch = fmaxf(ab, bb) - fminf(at, bt);
  float c2 = cw * cw + ch * ch + EPS;
  float dx = (al + ar) * 0.5f - (bl + br) * 0.5f;
  float dy = (at + ab) * 0.5f - (bt + bb) * 0.5f;
  float rho2 = dx * dx + dy * dy;
  float dat = atanA - atanB;
  float v = PI4 * (dat * dat);
  float alpha = v / (1.f - iou + v + EPS);
  return iou - rho2 / c2 - alpha * v;
}

// Decode-path CIoU: A={l,t,r,b}, E={cx,cy,atanA,areaA}; per-anchor values
// (areaB,cxb,cyb,atanB) hoisted; divisions via fastrcp (no VCC contention).
// Only feeds DISCRETE decisions (mask + ordering) -> fastrcp is safe.
__device__ __forceinline__ float dciou_h(float4 A, float4 E,
                                         float bl, float bt, float br, float bb,
                                         float areaB,
                                         float cxb, float cyb, float atanB) {
  float ltx = fmaxf(A.x, bl), lty = fmaxf(A.y, bt);
  float rbx = fminf(A.z, br), rby = fminf(A.w, bb);
  float wx = fmaxf(rbx - ltx, 0.f), wy = fmaxf(rby - lty, 0.f);
  float inter = wx * wy;
  float uni = E.w + areaB - inter;
  float iou = inter * fastrcp(uni + EPS);
  float cw = fmaxf(A.z, br) - fminf(A.x, bl);
  float ch = fmaxf(A.w, bb) - fminf(A.y, bt);
  float c2 = cw * cw + ch * ch + EPS;
  float dx = E.x - cxb;
  float dy = E.y - cyb;
  float rho2 = dx * dx + dy * dy;
  float dat = E.z - atanB;
  float v = PI4 * (dat * dat);
  float alpha = v * fastrcp(1.f - iou + v + EPS);
  return iou - rho2 * fastrcp(c2) - alpha * v;
}

__device__ __forceinline__ int wave_incl_scan(int x, int lane) {
  #pragma unroll
  for (int off = 1; off < 64; off <<= 1) {
    int y = __shfl_up(x, off);
    if (lane >= off) x += y;
  }
  return x;
}

// K1: decode pred boxes -> pltrb; mx over 50 GT boxes; composite sort key.
// 1 anchor/thread, grid (42, BB): ~21 waves/CU for latency hiding.
__global__ __launch_bounds__(256) void k_decode_mx(const float* __restrict__ p, const float* __restrict__ boxes,
                            float4* __restrict__ pltrb, unsigned long long* __restrict__ comp) {
  const int b = blockIdx.y;
  const int tid = threadIdx.x;
  const int j = blockIdx.x * 256 + tid;

  __shared__ float4 sA[NBOX];   // l,t,r,b
  __shared__ float4 sE[NBOX];   // cx,cy,atanA,areaA
  if (tid < NBOX) {
    const float* bp = boxes + (b * NBOX + tid) * 4;
    float l = bp[0], t = bp[1], r = bp[2], d = bp[3];
    sA[tid] = make_float4(l, t, r, d);
    float wa = r - l, ha = d - t;
    float cx = (l + r) * 0.5f, cy = (t + d) * 0.5f;
    sE[tid] = make_float4(cx, cy, atanf(wa / (ha + EPS)), wa * ha);
  }
  __syncthreads();
  if (j >= NT) return;

  int lvl, jb0, f;
  if (j < 8112)       { lvl = 0; jb0 = 0;     f = 52; }
  else if (j < 10140) { lvl = 1; jb0 = 8112;  f = 26; }
  else                { lvl = 2; jb0 = 10140; f = 13; }
  int jj = j - jb0;
  int cell = jj / 3, a = jj % 3 + lvl * 3;
  int x = cell % f, y = cell / f;
  float ff = (float)f;
  const float* pr = p + ((size_t)b * NT + j) * 25;
  float px = pr[0] / ff + (float)x / ff;
  float py = pr[1] / ff + (float)y / ff;
  float pw = expf(pr[2]) * c_aw[a];
  float ph = expf(pr[3]) * c_ah[a];
  float bl = px - pw * 0.5f, bt = py - ph * 0.5f;
  float br = px + pw * 0.5f, bbv = py + ph * 0.5f;
  pltrb[(size_t)b * NT + j] = make_float4(bl, bt, br, bbv);
  float wb = br - bl, hb = bbv - bt;
  float areab = wb * hb;
  float cxb = (bl + br) * 0.5f, cyb = (bt + bbv) * 0.5f;
  float atb = atanf(wb / (hb + EPS));

  float mx = -INFINITY;
  #pragma unroll 5
  for (int i = 0; i < NBOX; ++i) {
    float v = dciou_h(sA[i], sE[i], bl, bt, br, bbv, areab, cxb, cyb, atb);
    mx = fmaxf(mx, v);
  }

  float key = (mx < 0.5f) ? mx : INFINITY;
  unsigned int u = __float_as_uint(key);
  u = (u & 0x80000000u) ? ~u : (u | 0x80000000u);
  comp[(size_t)b * NT + j] = ((unsigned long long)u << 14) | (unsigned long long)j;
}

// K2 (fused select + scan + BCE): per-image 4-pass radix-histogram select of the
// 999th-smallest composite; then a fused cumsum(mask)-1 block scan over j to get
// the rank index used as the p-row (ref quirk), accumulating l_conf_n.
__global__ __launch_bounds__(1024) void k_neg2(const unsigned long long* __restrict__ comp,
                                               const float* __restrict__ p,
                                               float* __restrict__ lcn) {
  int b = blockIdx.x;
  const unsigned long long* c = comp + (size_t)b * NT;
  const int tid = threadIdx.x, lane = tid & 63, wave = tid >> 6;

  __shared__ int hist[4096];
  __shared__ int s_w[16];
  __shared__ unsigned long long s_pref;
  __shared__ int s_rem;
  __shared__ int s_carry;
  __shared__ int s_digit;
  __shared__ int s_rem_next;
  __shared__ float s_facc[16];

  // Hoist the image's composites into registers: 11 per thread (chunk-major).
  unsigned long long v[11];
  #pragma unroll
  for (int k = 0; k < 11; ++k) {
    int j = k * 1024 + tid;
    v[k] = (j < NT) ? c[j] : ~0ull;   // pad > any 46-bit composite; excluded by prefix check
  }

  if (tid == 0) { s_pref = 0ull; s_rem = NNEG - 1; s_carry = 0; }
  __syncthreads();

  // 4 radix passes over digit windows [47:36],[35:24],[23:12],[11:0].
  for (int pass = 0; pass < 4; ++pass) {
    int lo = 36 - pass * 12;
    for (int h = tid; h < 4096; h += 1024) hist[h] = 0;
    __syncthreads();
    unsigned long long pref = s_pref;
    #pragma unroll
    for (int k = 0; k < 11; ++k) {
      unsigned long long x = v[k];
      if ((x >> (lo + 12)) == (pref >> (lo + 12)))
        atomicAdd(&hist[(int)((x >> lo) & 4095ull)], 1);
    }
    __syncthreads();
    // Block-wide exclusive scan over 4096 buckets (4 per thread), locate target.
    int base = tid * 4;
    int c0 = hist[base], c1 = hist[base + 1], c2 = hist[base + 2], c3 = hist[base + 3];
    int tsum = c0 + c1 + c2 + c3;
    int incl = wave_incl_scan(tsum, lane);
    if (lane == 63) s_w[wave] = incl;
    __syncthreads();
    if (wave == 0) {
      int wv = (lane < 16) ? s_w[lane] : 0;
      int wincl = wave_incl_scan(wv, lane);
      if (lane < 16) s_w[lane] = wincl - wv;  // exclusive wave offsets
    }
    __syncthreads();
    int excl = incl - tsum + s_w[wave];
    int rem = s_rem;
    int p0 = excl, p1 = p0 + c0, p2 = p1 + c1, p3 = p2 + c2;
    if (rem >= p0 && rem < p0 + c0) { s_digit = base + 0; s_rem_next = rem - p0; }
    if (rem >= p1 && rem < p1 + c1) { s_digit = base + 1; s_rem_next = rem - p1; }
    if (rem >= p2 && rem < p2 + c2) { s_digit = base + 2; s_rem_next = rem - p2; }
    if (rem >= p3 && rem < p3 + c3) { s_digit = base + 3; s_rem_next = rem - p3; }
    __syncthreads();
    if (tid == 0) {
      s_pref |= ((unsigned long long)s_digit) << lo;
      s_rem = s_rem_next;
    }
    __syncthreads();
  }
  const unsigned long long T = s_pref;  // exact 999th-smallest composite (unique keys)

  // Fused scan (rank = cumsum(mask)-1) + selection (c<=T) + BCE accumulate.
  float acc = 0.f;
  const float* pb = p + (size_t)b * NT * 25;
  #pragma unroll
  for (int k = 0; k < 11; ++k) {
    unsigned long long x = v[k];
    int flag = ((x >> 14) < 0xFF800000ull) ? 1 : 0;  // finite ordkey => masked
    int incl = wave_incl_scan(flag, lane);
    if (lane == 63) s_w[wave] = incl;
    __syncthreads();
    if (wave == 0) {
      int wv = (lane < 16) ? s_w[lane] : 0;
      int wincl = wave_incl_scan(wv, lane);
      if (lane < 16) s_w[lane] = wincl - wv;
    }
    __syncthreads();
    int rank = s_carry + s_w[wave] + incl - 1;
    if (x <= T) {
      int idx = rank;
      if (idx < 0) idx += NT;  // JAX negative-index wrap (rank can be -1)
      float q = 1.f - pb[(size_t)idx * 25 + 4];
      q = fminf(fmaxf(q, EPS), 1.f - EPS);
      acc += -logf(q);
    }
    __syncthreads();
    if (tid == 1023) s_carry += s_w[15] + incl;  // chunk total
    __syncthreads();
  }

  // Reduce acc across the block.
  #pragma unroll
  for (int off = 32; off > 0; off >>= 1) acc += __shfl_down(acc, off);
  if (lane == 0) s_facc[wave] = acc;
  __syncthreads();
  if (tid == 0) {
    float s = 0.f;
    #pragma unroll
    for (int w = 0; w < 16; ++w) s += s_facc[w];
    lcn[b] = s;
  }
}

// K3: positive losses. One wave per (image, box): grid (NBOX, BB) x 64 threads.
__global__ __launch_bounds__(64) void k_pos(const float* __restrict__ p, const float* __restrict__ boxes,
                      const int* __restrict__ labels, const float4* __restrict__ pltrb,
                      float* __restrict__ pcls, float* __restrict__ pbox, float* __restrict__ pcp) {
  const int i = blockIdx.x;       // box
  const int b = blockIdx.y;       // image
  const int lane = threadIdx.x;   // 0..63

  __shared__ float scx[NBOX], scy[NBOX];
  if (lane < NBOX) {
    const float* bp = boxes + (b * NBOX + lane) * 4;
    float l = bp[0], t = bp[1], r = bp[2], d = bp[3];
    scx[lane] = (l + r) * 0.5f;
    scy[lane] = (t + d) * 0.5f;
  }
  __syncthreads();

  const float* bi = boxes + (b * NBOX + i) * 4;
  float bl0 = bi[0], bt0 = bi[1], br0 = bi[2], bd0 = bi[3];
  float fi = (float)i;
  float al = bl0 + fi, at = bt0 + fi, ar = br0 + fi, ad = bd0 + fi;
  float wa = ar - al, ha = ad - at;
  float atanA = atanf(wa / (ha + EPS));

  float bestv = -INFINITY; int bestm = 1 << 30;
  #pragma unroll
  for (int m = lane; m < 9 * NBOX; m += 64) {
    int jb = m / 9, a = m % 9;
    float fa = (a < 3) ? 52.f : (a < 6 ? 26.f : 13.f);
    float col = floorf(scx[jb] * fa);
    float row = floorf(scy[jb] * fa);
    float ax = col / fa, ay = row / fa;
    float aw = c_aw[a], ah = c_ah[a];
    float fj = (float)jb;
    float bl = (ax - aw * 0.5f) + fj;
    float bt = (ay - ah * 0.5f) + fj;
    float br = (ax + aw * 0.5f) + fj;
    float bd = (ay + ah * 0.5f) + fj;
    float wb = br - bl, hb = bd - bt;
    float atanB = atanf(wb / (hb + EPS));
    float v = dciou(al, at, ar, ad, bl, bt, br, bd, atanA, atanB);
    if (v > bestv) { bestv = v; bestm = m; }
  }
  #pragma unroll
  for (int off = 32; off > 0; off >>= 1) {
    float ov = __shfl_down(bestv, off);
    int om = __shfl_down(bestm, off);
    if (ov > bestv || (ov == bestv && om < bestm)) { bestv = ov; bestm = om; }
  }
  int bm = __shfl(bestm, 0);

  int k = bm % 9;
  int lvl = k / 3;
  float fk = (k < 3) ? 52.f : (k < 6 ? 26.f : 13.f);
  float col = floorf(scx[i] * fk);
  float row = floorf(scy[i] * fk);
  float offc = (lvl == 0) ? 0.f : (lvl == 1 ? 2704.f : 3380.f);
  int midx = (int)((offc + row * fk + col) * 3.0f + (float)lvl);  // ref uses +lvl, not +k%3

  const float* pr = p + ((size_t)b * NT + midx) * 25;
  int lab = labels[b * NBOX + i] - 1;

  float lc = 0.f;
  if (lane < NCLS) {
    float pc = pr[5 + lane];
    pc = fminf(fmaxf(pc, EPS), 1.f - EPS);
    float tt = (lane == lab) ? 1.f : 0.f;
    lc = -(tt * logf(pc) + (1.f - tt) * logf(1.f - pc));
  }
  #pragma unroll
  for (int off = 32; off > 0; off >>= 1) lc += __shfl_down(lc, off);

  if (lane == 0) {
    pcls[b * NBOX + i] = lc;
    float pc4 = pr[4];
    pc4 = fminf(fmaxf(pc4, EPS), 1.f - EPS);
    pcp[b * NBOX + i] = -logf(pc4);
    float4 pb4 = pltrb[(size_t)b * NT + midx];
    float wb = pb4.z - pb4.x, hb = pb4.w - pb4.y;
    float atanB = atanf(wb / (hb + EPS));
    float wa0 = br0 - bl0, ha0 = bd0 - bt0;
    float atanA0 = atanf(wa0 / (ha0 + EPS));
    float cp = dciou(bl0, bt0, br0, bd0, pb4.x, pb4.y, pb4.z, pb4.w, atanA0, atanB);
    float w = 2.f - wa0 * ha0;
    pbox[b * NBOX + i] = w * (1.f - cp);
  }
}

// K4: final reduce. Lane b (<32) sums its image's 50 per-box partials + lcn.
__global__ void k_final(const float* __restrict__ pcls, const float* __restrict__ pbox,
                        const float* __restrict__ pcp, const float* __restrict__ lcn,
                        float* __restrict__ out) {
  int lane = threadIdx.x;
  float s = 0.f;
  if (lane < BB) {
    float a = 0.f, bx = 0.f, cp = 0.f;
    for (int i = 0; i < NBOX; ++i) {
      a  += pcls[lane * NBOX + i];
      bx += pbox[lane * NBOX + i];
      cp += pcp[lane * NBOX + i];
    }
    s = (a + bx + cp) / (float)NBOX + lcn[lane];
  }
  #pragma unroll
  for (int off = 32; off > 0; off >>= 1) s += __shfl_down(s, off);
  if (lane == 0) out[0] = s / (float)BB;
}

}  // namespace

extern "C" void kernel_launch(void* const* d_in, const int* in_sizes, int n_in,
                              void* d_out, int out_size, void* d_ws, size_t ws_size,
                              hipStream_t stream) {
  const float* p      = (const float*)d_in[0];
  const float* boxes  = (const float*)d_in[1];
  const int*   labels = (const int*)d_in[2];
  float* out = (float*)d_out;

  char* ws = (char*)d_ws;
  size_t off = 0;
  float4* pltrb = (float4*)(ws + off);             off += (size_t)BB * NT * sizeof(float4);
  unsigned long long* comp = (unsigned long long*)(ws + off); off += (size_t)BB * NT * sizeof(unsigned long long);
  float* pcls = (float*)(ws + off);                off += BB * NBOX * sizeof(float);
  float* pbox = (float*)(ws + off);                off += BB * NBOX * sizeof(float);
  float* pcp  = (float*)(ws + off);                off += BB * NBOX * sizeof(float);
  float* lcn  = (float*)(ws + off);                off += BB * sizeof(float);

  dim3 g1((NT + 255) / 256, BB);
  k_decode_mx<<<g1, 256, 0, stream>>>(p, boxes, pltrb, comp);
  k_neg2<<<BB, 1024, 0, stream>>>(comp, p, lcn);
  k_pos<<<dim3(NBOX, BB), 64, 0, stream>>>(p, boxes, labels, pltrb, pcls, pbox, pcp);
  k_final<<<1, 64, 0, stream>>>(pcls, pbox, pcp, lcn, out);
}

// Round 7
// 70.025 us; speedup vs baseline: 6.8888x; 1.0119x over previous
//
#include <hip/hip_runtime.h>

namespace {

constexpr int BB   = 32;     // batch
constexpr int NBOX = 50;
constexpr int NCLS = 20;
constexpr int NT   = 10647;  // total anchors
constexpr int NNEG = 1000;
constexpr float EPS = 1e-7f;
constexpr float PI4 = (float)(4.0 / 9.869604401089358);  // 4/pi^2

__device__ __constant__ float c_aw[9] = {10.f/416.f,16.f/416.f,33.f/416.f,30.f/416.f,62.f/416.f,59.f/416.f,116.f/416.f,156.f/416.f,373.f/416.f};
__device__ __constant__ float c_ah[9] = {13.f/416.f,30.f/416.f,23.f/416.f,61.f/416.f,45.f/416.f,119.f/416.f,90.f/416.f,198.f/416.f,326.f/416.f};

// rcp + 1 Newton-Raphson step: ~1ulp, no VCC (v_div_scale/v_div_fmas) serialization.
__device__ __forceinline__ float fastrcp(float x) {
  float r = __builtin_amdgcn_rcpf(x);
  r = fmaf(fmaf(-x, r, 1.f), r, r);
  return r;
}

__device__ __forceinline__ float dciou(float al, float at, float ar, float ab,
                                       float bl, float bt, float br, float bb,
                                       float atanA, float atanB) {
  float ltx = fmaxf(al, bl), lty = fmaxf(at, bt);
  float rbx = fminf(ar, br), rby = fminf(ab, bb);
  float wx = fmaxf(rbx - ltx, 0.f), wy = fmaxf(rby - lty, 0.f);
  float inter = wx * wy;
  float wa = ar - al, ha = ab - at;
  float wb = br - bl, hb = bb - bt;
  float uni = wa * ha + wb * hb - inter;
  float iou = inter / (uni + EPS);
  float cw = fmaxf(ar, br) - fminf(al, bl);
  float ch = fmaxf(ab, bb) - fminf(at, bt);
  float c2 = cw * cw + ch * ch + EPS;
  float dx = (al + ar) * 0.5f - (bl + br) * 0.5f;
  float dy = (at + ab) * 0.5f - (bt + bb) * 0.5f;
  float rho2 = dx * dx + dy * dy;
  float dat = atanA - atanB;
  float v = PI4 * (dat * dat);
  float alpha = v / (1.f - iou + v + EPS);
  return iou - rho2 / c2 - alpha * v;
}

// Decode-path CIoU: A={l,t,r,b}, E={cx,cy,atanA,areaA}; per-anchor values
// (areaB,cxb,cyb,atanB) hoisted; divisions via fastrcp (no VCC contention).
// Only feeds DISCRETE decisions (mask + ordering) -> fastrcp is safe.
__device__ __forceinline__ float dciou_h(float4 A, float4 E,
                                         float bl, float bt, float br, float bb,
                                         float areaB,
                                         float cxb, float cyb, float atanB) {
  float ltx = fmaxf(A.x, bl), lty = fmaxf(A.y, bt);
  float rbx = fminf(A.z, br), rby = fminf(A.w, bb);
  float wx = fmaxf(rbx - ltx, 0.f), wy = fmaxf(rby - lty, 0.f);
  float inter = wx * wy;
  float uni = E.w + areaB - inter;
  float iou = inter * fastrcp(uni + EPS);
  float cw = fmaxf(A.z, br) - fminf(A.x, bl);
  float ch = fmaxf(A.w, bb) - fminf(A.y, bt);
  float c2 = cw * cw + ch * ch + EPS;
  float dx = E.x - cxb;
  float dy = E.y - cyb;
  float rho2 = dx * dx + dy * dy;
  float dat = E.z - atanB;
  float v = PI4 * (dat * dat);
  float alpha = v * fastrcp(1.f - iou + v + EPS);
  return iou - rho2 * fastrcp(c2) - alpha * v;
}

__device__ __forceinline__ int wave_incl_scan(int x, int lane) {
  #pragma unroll
  for (int off = 1; off < 64; off <<= 1) {
    int y = __shfl_up(x, off);
    if (lane >= off) x += y;
  }
  return x;
}

// K1: decode pred boxes; mx over 50 GT boxes (dual independent chains for ILP);
// composite sort key. 1 anchor/thread, grid (42, BB).
__global__ __launch_bounds__(256) void k_decode_mx(const float* __restrict__ p, const float* __restrict__ boxes,
                            unsigned long long* __restrict__ comp) {
  const int b = blockIdx.y;
  const int tid = threadIdx.x;
  const int j = blockIdx.x * 256 + tid;

  __shared__ float4 sA[NBOX];   // l,t,r,b
  __shared__ float4 sE[NBOX];   // cx,cy,atanA,areaA
  if (tid < NBOX) {
    const float* bp = boxes + (b * NBOX + tid) * 4;
    float l = bp[0], t = bp[1], r = bp[2], d = bp[3];
    sA[tid] = make_float4(l, t, r, d);
    float wa = r - l, ha = d - t;
    float cx = (l + r) * 0.5f, cy = (t + d) * 0.5f;
    sE[tid] = make_float4(cx, cy, atanf(wa / (ha + EPS)), wa * ha);
  }
  __syncthreads();
  if (j >= NT) return;

  int lvl, jb0, f;
  if (j < 8112)       { lvl = 0; jb0 = 0;     f = 52; }
  else if (j < 10140) { lvl = 1; jb0 = 8112;  f = 26; }
  else                { lvl = 2; jb0 = 10140; f = 13; }
  int jj = j - jb0;
  int cell = jj / 3, a = jj % 3 + lvl * 3;
  int x = cell % f, y = cell / f;
  float ff = (float)f;
  const float* pr = p + ((size_t)b * NT + j) * 25;
  float px = pr[0] / ff + (float)x / ff;
  float py = pr[1] / ff + (float)y / ff;
  float pw = expf(pr[2]) * c_aw[a];
  float ph = expf(pr[3]) * c_ah[a];
  float bl = px - pw * 0.5f, bt = py - ph * 0.5f;
  float br = px + pw * 0.5f, bbv = py + ph * 0.5f;
  float wb = br - bl, hb = bbv - bt;
  float areab = wb * hb;
  float cxb = (bl + br) * 0.5f, cyb = (bt + bbv) * 0.5f;
  float atb = atanf(wb / (hb + EPS));

  // Two independent accumulator chains (max is exactly associative).
  float mx0 = -INFINITY, mx1 = -INFINITY;
  #pragma unroll 5
  for (int i = 0; i < NBOX; i += 2) {
    float v0 = dciou_h(sA[i],     sE[i],     bl, bt, br, bbv, areab, cxb, cyb, atb);
    float v1 = dciou_h(sA[i + 1], sE[i + 1], bl, bt, br, bbv, areab, cxb, cyb, atb);
    mx0 = fmaxf(mx0, v0);
    mx1 = fmaxf(mx1, v1);
  }
  float mx = fmaxf(mx0, mx1);

  float key = (mx < 0.5f) ? mx : INFINITY;
  unsigned int u = __float_as_uint(key);
  u = (u & 0x80000000u) ? ~u : (u | 0x80000000u);
  comp[(size_t)b * NT + j] = ((unsigned long long)u << 14) | (unsigned long long)j;
}

// K2 (fused select + scan + BCE): per-image 4-pass radix-histogram select of the
// 999th-smallest composite; then a fused cumsum(mask)-1 block scan over j to get
// the rank index used as the p-row (ref quirk), accumulating l_conf_n.
__global__ __launch_bounds__(1024) void k_neg2(const unsigned long long* __restrict__ comp,
                                               const float* __restrict__ p,
                                               float* __restrict__ lcn) {
  int b = blockIdx.x;
  const unsigned long long* c = comp + (size_t)b * NT;
  const int tid = threadIdx.x, lane = tid & 63, wave = tid >> 6;

  __shared__ int hist[4096];
  __shared__ int s_w[16];
  __shared__ unsigned long long s_pref;
  __shared__ int s_rem;
  __shared__ int s_carry;
  __shared__ int s_digit;
  __shared__ int s_rem_next;
  __shared__ float s_facc[16];

  // Hoist the image's composites into registers: 11 per thread (chunk-major).
  unsigned long long v[11];
  #pragma unroll
  for (int k = 0; k < 11; ++k) {
    int j = k * 1024 + tid;
    v[k] = (j < NT) ? c[j] : ~0ull;   // pad > any 46-bit composite; excluded by prefix check
  }

  if (tid == 0) { s_pref = 0ull; s_rem = NNEG - 1; s_carry = 0; }
  __syncthreads();

  // 4 radix passes over digit windows [47:36],[35:24],[23:12],[11:0].
  for (int pass = 0; pass < 4; ++pass) {
    int lo = 36 - pass * 12;
    for (int h = tid; h < 4096; h += 1024) hist[h] = 0;
    __syncthreads();
    unsigned long long pref = s_pref;
    #pragma unroll
    for (int k = 0; k < 11; ++k) {
      unsigned long long x = v[k];
      if ((x >> (lo + 12)) == (pref >> (lo + 12)))
        atomicAdd(&hist[(int)((x >> lo) & 4095ull)], 1);
    }
    __syncthreads();
    // Block-wide exclusive scan over 4096 buckets (4 per thread), locate target.
    int base = tid * 4;
    int c0 = hist[base], c1 = hist[base + 1], c2 = hist[base + 2], c3 = hist[base + 3];
    int tsum = c0 + c1 + c2 + c3;
    int incl = wave_incl_scan(tsum, lane);
    if (lane == 63) s_w[wave] = incl;
    __syncthreads();
    if (wave == 0) {
      int wv = (lane < 16) ? s_w[lane] : 0;
      int wincl = wave_incl_scan(wv, lane);
      if (lane < 16) s_w[lane] = wincl - wv;  // exclusive wave offsets
    }
    __syncthreads();
    int excl = incl - tsum + s_w[wave];
    int rem = s_rem;
    int p0 = excl, p1 = p0 + c0, p2 = p1 + c1, p3 = p2 + c2;
    if (rem >= p0 && rem < p0 + c0) { s_digit = base + 0; s_rem_next = rem - p0; }
    if (rem >= p1 && rem < p1 + c1) { s_digit = base + 1; s_rem_next = rem - p1; }
    if (rem >= p2 && rem < p2 + c2) { s_digit = base + 2; s_rem_next = rem - p2; }
    if (rem >= p3 && rem < p3 + c3) { s_digit = base + 3; s_rem_next = rem - p3; }
    __syncthreads();
    if (tid == 0) {
      s_pref |= ((unsigned long long)s_digit) << lo;
      s_rem = s_rem_next;
    }
    __syncthreads();
  }
  const unsigned long long T = s_pref;  // exact 999th-smallest composite (unique keys)

  // Fused scan (rank = cumsum(mask)-1) + selection (c<=T) + BCE accumulate.
  float acc = 0.f;
  const float* pb = p + (size_t)b * NT * 25;
  #pragma unroll
  for (int k = 0; k < 11; ++k) {
    unsigned long long x = v[k];
    int flag = ((x >> 14) < 0xFF800000ull) ? 1 : 0;  // finite ordkey => masked
    int incl = wave_incl_scan(flag, lane);
    if (lane == 63) s_w[wave] = incl;
    __syncthreads();
    if (wave == 0) {
      int wv = (lane < 16) ? s_w[lane] : 0;
      int wincl = wave_incl_scan(wv, lane);
      if (lane < 16) s_w[lane] = wincl - wv;
    }
    __syncthreads();
    int rank = s_carry + s_w[wave] + incl - 1;
    if (x <= T) {
      int idx = rank;
      if (idx < 0) idx += NT;  // JAX negative-index wrap (rank can be -1)
      float q = 1.f - pb[(size_t)idx * 25 + 4];
      q = fminf(fmaxf(q, EPS), 1.f - EPS);
      acc += -logf(q);
    }
    __syncthreads();
    if (tid == 1023) s_carry += s_w[15] + incl;  // chunk total
    __syncthreads();
  }

  // Reduce acc across the block.
  #pragma unroll
  for (int off = 32; off > 0; off >>= 1) acc += __shfl_down(acc, off);
  if (lane == 0) s_facc[wave] = acc;
  __syncthreads();
  if (tid == 0) {
    float s = 0.f;
    #pragma unroll
    for (int w = 0; w < 16; ++w) s += s_facc[w];
    lcn[b] = s;
  }
}

// K3: positive losses. One wave per (image, box): grid (NBOX, BB) x 64 threads.
// Pred box for midx is re-derived from p (bit-identical to reference decode).
__global__ __launch_bounds__(64) void k_pos(const float* __restrict__ p, const float* __restrict__ boxes,
                      const int* __restrict__ labels,
                      float* __restrict__ pcls, float* __restrict__ pbox, float* __restrict__ pcp) {
  const int i = blockIdx.x;       // box
  const int b = blockIdx.y;       // image
  const int lane = threadIdx.x;   // 0..63

  __shared__ float scx[NBOX], scy[NBOX];
  if (lane < NBOX) {
    const float* bp = boxes + (b * NBOX + lane) * 4;
    float l = bp[0], t = bp[1], r = bp[2], d = bp[3];
    scx[lane] = (l + r) * 0.5f;
    scy[lane] = (t + d) * 0.5f;
  }
  __syncthreads();

  const float* bi = boxes + (b * NBOX + i) * 4;
  float bl0 = bi[0], bt0 = bi[1], br0 = bi[2], bd0 = bi[3];
  float fi = (float)i;
  float al = bl0 + fi, at = bt0 + fi, ar = br0 + fi, ad = bd0 + fi;
  float wa = ar - al, ha = ad - at;
  float atanA = atanf(wa / (ha + EPS));

  float bestv = -INFINITY; int bestm = 1 << 30;
  #pragma unroll
  for (int m = lane; m < 9 * NBOX; m += 64) {
    int jb = m / 9, a = m % 9;
    float fa = (a < 3) ? 52.f : (a < 6 ? 26.f : 13.f);
    float col = floorf(scx[jb] * fa);
    float row = floorf(scy[jb] * fa);
    float ax = col / fa, ay = row / fa;
    float aw = c_aw[a], ah = c_ah[a];
    float fj = (float)jb;
    float bl = (ax - aw * 0.5f) + fj;
    float bt = (ay - ah * 0.5f) + fj;
    float br = (ax + aw * 0.5f) + fj;
    float bd = (ay + ah * 0.5f) + fj;
    float wb = br - bl, hb = bd - bt;
    float atanB = atanf(wb / (hb + EPS));
    float v = dciou(al, at, ar, ad, bl, bt, br, bd, atanA, atanB);
    if (v > bestv) { bestv = v; bestm = m; }
  }
  #pragma unroll
  for (int off = 32; off > 0; off >>= 1) {
    float ov = __shfl_down(bestv, off);
    int om = __shfl_down(bestm, off);
    if (ov > bestv || (ov == bestv && om < bestm)) { bestv = ov; bestm = om; }
  }
  int bm = __shfl(bestm, 0);

  int k = bm % 9;
  int lvl = k / 3;
  float fk = (k < 3) ? 52.f : (k < 6 ? 26.f : 13.f);
  float col = floorf(scx[i] * fk);
  float row = floorf(scy[i] * fk);
  float offc = (lvl == 0) ? 0.f : (lvl == 1 ? 2704.f : 3380.f);
  int midx = (int)((offc + row * fk + col) * 3.0f + (float)lvl);  // ref uses +lvl, not +k%3

  const float* pr = p + ((size_t)b * NT + midx) * 25;
  int lab = labels[b * NBOX + i] - 1;

  float lc = 0.f;
  if (lane < NCLS) {
    float pc = pr[5 + lane];
    pc = fminf(fmaxf(pc, EPS), 1.f - EPS);
    float tt = (lane == lab) ? 1.f : 0.f;
    lc = -(tt * logf(pc) + (1.f - tt) * logf(1.f - pc));
  }
  #pragma unroll
  for (int off = 32; off > 0; off >>= 1) lc += __shfl_down(lc, off);

  if (lane == 0) {
    pcls[b * NBOX + i] = lc;
    float pc4 = pr[4];
    pc4 = fminf(fmaxf(pc4, EPS), 1.f - EPS);
    pcp[b * NBOX + i] = -logf(pc4);

    // Re-derive pred ltrb for row midx (same expressions as reference decode).
    int lvl2, jb0, f2;
    if (midx < 8112)       { lvl2 = 0; jb0 = 0;     f2 = 52; }
    else if (midx < 10140) { lvl2 = 1; jb0 = 8112;  f2 = 26; }
    else                   { lvl2 = 2; jb0 = 10140; f2 = 13; }
    int jj2 = midx - jb0;
    int cell2 = jj2 / 3, a2 = jj2 % 3 + lvl2 * 3;
    int xx = cell2 % f2, yy = cell2 / f2;
    float ff2 = (float)f2;
    float px = pr[0] / ff2 + (float)xx / ff2;
    float py = pr[1] / ff2 + (float)yy / ff2;
    float pw = expf(pr[2]) * c_aw[a2];
    float ph = expf(pr[3]) * c_ah[a2];
    float pbl = px - pw * 0.5f, pbt = py - ph * 0.5f;
    float pbr = px + pw * 0.5f, pbd = py + ph * 0.5f;

    float wb = pbr - pbl, hb = pbd - pbt;
    float atanB = atanf(wb / (hb + EPS));
    float wa0 = br0 - bl0, ha0 = bd0 - bt0;
    float atanA0 = atanf(wa0 / (ha0 + EPS));
    float cp = dciou(bl0, bt0, br0, bd0, pbl, pbt, pbr, pbd, atanA0, atanB);
    float w = 2.f - wa0 * ha0;
    pbox[b * NBOX + i] = w * (1.f - cp);
  }
}

// K4: final reduce. Lane b (<32) sums its image's 50 per-box partials + lcn.
__global__ void k_final(const float* __restrict__ pcls, const float* __restrict__ pbox,
                        const float* __restrict__ pcp, const float* __restrict__ lcn,
                        float* __restrict__ out) {
  int lane = threadIdx.x;
  float s = 0.f;
  if (lane < BB) {
    float a = 0.f, bx = 0.f, cp = 0.f;
    for (int i = 0; i < NBOX; ++i) {
      a  += pcls[lane * NBOX + i];
      bx += pbox[lane * NBOX + i];
      cp += pcp[lane * NBOX + i];
    }
    s = (a + bx + cp) / (float)NBOX + lcn[lane];
  }
  #pragma unroll
  for (int off = 32; off > 0; off >>= 1) s += __shfl_down(s, off);
  if (lane == 0) out[0] = s / (float)BB;
}

}  // namespace

extern "C" void kernel_launch(void* const* d_in, const int* in_sizes, int n_in,
                              void* d_out, int out_size, void* d_ws, size_t ws_size,
                              hipStream_t stream) {
  const float* p      = (const float*)d_in[0];
  const float* boxes  = (const float*)d_in[1];
  const int*   labels = (const int*)d_in[2];
  float* out = (float*)d_out;

  char* ws = (char*)d_ws;
  size_t off = 0;
  unsigned long long* comp = (unsigned long long*)(ws + off); off += (size_t)BB * NT * sizeof(unsigned long long);
  float* pcls = (float*)(ws + off);                off += BB * NBOX * sizeof(float);
  float* pbox = (float*)(ws + off);                off += BB * NBOX * sizeof(float);
  float* pcp  = (float*)(ws + off);                off += BB * NBOX * sizeof(float);
  float* lcn  = (float*)(ws + off);                off += BB * sizeof(float);

  dim3 g1((NT + 255) / 256, BB);
  k_decode_mx<<<g1, 256, 0, stream>>>(p, boxes, comp);
  k_neg2<<<BB, 1024, 0, stream>>>(comp, p, lcn);
  k_pos<<<dim3(NBOX, BB), 64, 0, stream>>>(p, boxes, labels, pcls, pbox, pcp);
  k_final<<<1, 64, 0, stream>>>(pcls, pbox, pcp, lcn, out);
}